// Round 6
// baseline (691.882 us; speedup 1.0000x reference)
//
#include <hip/hip_runtime.h>

#define BB   4
#define SS   2048
#define HH   16
#define DM   1024
#define DKV  64
#define LNEPS 1e-6f

#define MD_BF16 0
#define MD_F32  1
#define MD_F16  2

typedef __attribute__((ext_vector_type(8))) short bf16x8;
typedef __attribute__((ext_vector_type(4))) float f32x4;
#define MFMA16(a,b,c) __builtin_amdgcn_mfma_f32_16x16x32_bf16(a,b,c,0,0,0)

// async global->LDS DMA, 16B per lane (dest = wave-uniform base + lane*16)
__device__ __forceinline__ void gl_lds16(const ushort* g, ushort* l) {
    __builtin_amdgcn_global_load_lds(
        (const __attribute__((address_space(1))) void*)g,
        (__attribute__((address_space(3))) void*)l, 16, 0, 0);
}
__device__ __forceinline__ void wait_vm0_barrier() {
    asm volatile("s_waitcnt vmcnt(0)" ::: "memory");
    __builtin_amdgcn_s_barrier();
}

// ---------- dtype helpers ----------
__device__ __forceinline__ float2 unpack2(unsigned int u) {
    union { unsigned int i; float f; } a, b;
    a.i = u << 16;
    b.i = u & 0xffff0000u;
    return make_float2(a.f, b.f);
}
__device__ __forceinline__ unsigned short f2bf(float f) {   // RNE
    union { float f; unsigned int i; } c; c.f = f;
    unsigned int u = c.i;
    unsigned int r = u + 0x7fffu + ((u >> 16) & 1u);
    return (unsigned short)(r >> 16);
}
__device__ __forceinline__ unsigned short f2bf_t(float f) { // truncate
    union { float f; unsigned int i; } c; c.f = f;
    return (unsigned short)(c.i >> 16);
}
__device__ __forceinline__ float h2f(unsigned int bits16) {
    unsigned short s = (unsigned short)bits16;
    _Float16 x;
    __builtin_memcpy(&x, &s, 2);
    return (float)x;
}
__device__ __forceinline__ void load4m(const void* p, int mode, size_t e0, float* o) {
    if (mode == MD_F32) {
        float4 v = *(const float4*)((const float*)p + e0);
        o[0] = v.x; o[1] = v.y; o[2] = v.z; o[3] = v.w;
    } else {
        uint2 u = *(const uint2*)((const ushort*)p + e0);
        if (mode == MD_BF16) {
            float2 a = unpack2(u.x), b = unpack2(u.y);
            o[0] = a.x; o[1] = a.y; o[2] = b.x; o[3] = b.y;
        } else {
            o[0] = h2f(u.x & 0xFFFFu); o[1] = h2f(u.x >> 16);
            o[2] = h2f(u.y & 0xFFFFu); o[3] = h2f(u.y >> 16);
        }
    }
}
__device__ __forceinline__ float loadS(const void* p, int mode, size_t i) {
    if (mode == MD_F32) return ((const float*)p)[i];
    unsigned short u = ((const ushort*)p)[i];
    if (mode == MD_BF16) { union { unsigned i; float f; } c; c.i = (unsigned)u << 16; return c.f; }
    return h2f(u);
}

// raw 16-elem load + convert (same rounding chain as all prior rounds)
__device__ __forceinline__ void loadAraw(const void* p, int m, size_t e, uint4* r) {
    if (m == MD_F32) {
        const float* f = (const float*)p + e;
        r[0] = *(const uint4*)(f);
        r[1] = *(const uint4*)(f + 4);
        r[2] = *(const uint4*)(f + 8);
        r[3] = *(const uint4*)(f + 12);
    } else {
        const ushort* s = (const ushort*)p + e;
        r[0] = *(const uint4*)s;
        r[1] = *(const uint4*)(s + 8);
    }
}
__device__ __forceinline__ void cvtA16(const uint4* r, int m, uint4* o2) {
    union { ushort u[16]; uint4 v[2]; } o;
    if (m == MD_F32) {
        const float* f = (const float*)r;
#pragma unroll
        for (int j = 0; j < 16; ++j) o.u[j] = f2bf(f[j]);
    } else if (m == MD_BF16) {
        o.v[0] = r[0]; o.v[1] = r[1];
    } else {
        const ushort* s = (const ushort*)r;
#pragma unroll
        for (int j = 0; j < 16; ++j) o.u[j] = f2bf(h2f(s[j]));
    }
    o2[0] = o.v[0]; o2[1] = o.v[1];
}

// per-block dtype sniff (same function of same bytes everywhere)
__device__ __forceinline__ int sniff_local(const void* p_, int nhalf) {
    __shared__ int cE, cO;
    const ushort* p = (const ushort*)p_;
    if (threadIdx.x == 0) { cE = 0; cO = 0; }
    __syncthreads();
    int e = 0, o = 0;
    for (int i = threadIdx.x; i < nhalf; i += 256) {
        unsigned ex = (p[i] >> 7) & 0xFFu;
        int hit = (ex < 100u || ex == 0xFFu) ? 1 : 0;
        if (i & 1) o += hit; else e += hit;
    }
    atomicAdd(&cE, e);
    atomicAdd(&cO, o);
    __syncthreads();
    const int total = cE + cO;
    return (total < 48) ? MD_BF16 : ((cO * 4 < cE) ? MD_F32 : MD_F16);
}

// ---------- shared bodies ----------
__device__ __forceinline__ void wtrans_body(
    const void* __restrict__ W, ushort* __restrict__ Wt, int m, int sub)
{
    __shared__ ushort T[64][68];
    const int tid = threadIdx.x;
    const int n0 = (sub & 15) * 64, k0 = (sub >> 4) * 64;

    const int r = tid >> 2, c = (tid & 3) * 16;
    float t[4];
#pragma unroll
    for (int j = 0; j < 4; ++j) {
        load4m(W, m, (size_t)(k0 + r) * DM + n0 + c + 4 * j, t);
#pragma unroll
        for (int i = 0; i < 4; ++i) T[r][c + 4 * j + i] = f2bf(t[i]);
    }
    __syncthreads();

    const int rn = tid >> 2, ck = (tid & 3) * 16;
    union { ushort u[8]; uint4 v; } p0, p1;
#pragma unroll
    for (int j = 0; j < 8; ++j) { p0.u[j] = T[ck + j][rn]; p1.u[j] = T[ck + 8 + j][rn]; }
    ushort* op = &Wt[(size_t)(n0 + rn) * DM + k0 + ck];
    *(uint4*)op = p0.v;
    *(uint4*)(op + 8) = p1.v;
}

__device__ __forceinline__ void aconv_body(
    const void* __restrict__ A, ushort* __restrict__ Ab, int bidl)
{
    const int m = sniff_local(A, 4096);
    const size_t e0 = ((size_t)bidl * 256 + threadIdx.x) * 16;
    uint4 r[4], o[2];
    loadAraw(A, m, e0, r);
    cvtA16(r, m, o);
    *(uint4*)&Ab[e0]     = o[0];
    *(uint4*)&Ab[e0 + 8] = o[1];
}

// =====================================================================
// prep (one launch, 7168 blocks):
//   [0,2048)    mask bit-pack -> pm (2MB)
//   [2048,3072) 4x weight transpose (w_qs,w_ks,w_vs,w_out -> Wt*)
//   [3072,5120) aconv(query) -> Abq
//   [5120,7168) aconv(value) -> Abv
// =====================================================================
__global__ __launch_bounds__(256) void prep(
    const int* __restrict__ mask, unsigned int* __restrict__ pm,
    const void* __restrict__ w_qs, const void* __restrict__ w_ks,
    const void* __restrict__ w_vs, const void* __restrict__ w_out,
    ushort* __restrict__ Wtq, ushort* __restrict__ Wtk,
    ushort* __restrict__ Wtv, ushort* __restrict__ Wt2,
    const void* __restrict__ query, const void* __restrict__ value,
    ushort* __restrict__ Abq, ushort* __restrict__ Abv)
{
    const int bid = blockIdx.x;
    if (bid < 2048) {
        const int w = bid * 256 + threadIdx.x;
        const int* p = mask + (size_t)w * 32;
        unsigned int bits = 0u;
#pragma unroll
        for (int j = 0; j < 8; ++j) {
            int4 v = *(const int4*)(p + j * 4);
            bits |= (v.x ? 1u : 0u) << (4 * j);
            bits |= (v.y ? 1u : 0u) << (4 * j + 1);
            bits |= (v.z ? 1u : 0u) << (4 * j + 2);
            bits |= (v.w ? 1u : 0u) << (4 * j + 3);
        }
        pm[w] = bits;
    } else if (bid < 3072) {
        const int b2 = bid - 2048;
        const int g = b2 >> 8, sub = b2 & 255;
        const void* W = (g == 0) ? w_qs : (g == 1) ? w_ks : (g == 2) ? w_vs : w_out;
        ushort* Wt = (g == 0) ? Wtq : (g == 1) ? Wtk : (g == 2) ? Wtv : Wt2;
        wtrans_body(W, Wt, sniff_local(W, 4096), sub);
    } else if (bid < 5120) {
        aconv_body(query, Abq, bid - 3072);
    } else {
        aconv_body(value, Abv, bid - 5120);
    }
}

// standalone aconv for key (runs after projqv frees the Abv/Xw region)
__global__ __launch_bounds__(256) void aconv_k(
    const void* __restrict__ A, ushort* __restrict__ Ab)
{
    aconv_body(A, Ab, blockIdx.x);
}

// =====================================================================
// MFMA projection GEMM (round-3 proven body): A bf16 @ Wt[n][k] bf16.
// 128x128 tile, BK=32, dbuf global_load_lds, XCD-chunked swizzle.
// z selects the (A, Wt, Out, vmode, scale) tuple.
// =====================================================================
struct ProjArgs {
    const ushort* A[2]; const ushort* Wt[2]; ushort* Out[2];
    int vmode[2]; float scale[2];
};

__global__ __launch_bounds__(256) void proj_mfma(ProjArgs pa)
{
    __shared__ __align__(16) ushort Asf[2][4096];
    __shared__ __align__(16) ushort Bsf[2][4096];

    const int z = blockIdx.z;
    const ushort* A  = pa.A[z];
    const ushort* Wt = pa.Wt[z];
    ushort* Out = pa.Out[z];
    const int vmode = pa.vmode[z];
    const float scale = pa.scale[z];

    const int tid = threadIdx.x;
    const int lane = tid & 63, wv = tid >> 6;
    const int quad = lane >> 4, L = lane & 15;
    const int bid = blockIdx.y * gridDim.x + blockIdx.x;   // 512 per z
    const int swz = (bid & 7) * 64 + (bid >> 3);           // XCD-chunked
    const int m0 = (swz >> 3) * 128, n0 = (swz & 7) * 128;
    const int wm = (wv >> 1) * 64, wn = (wv & 1) * 64;

    const int e0 = (wv * 2 + 0) * 512 + lane * 8;
    const int e1 = (wv * 2 + 1) * 512 + lane * 8;
    const ushort* gA0 = A  + (size_t)(m0 + (e0 >> 5)) * DM + (e0 & 31);
    const ushort* gA1 = A  + (size_t)(m0 + (e1 >> 5)) * DM + (e1 & 31);
    const ushort* gB0 = Wt + (size_t)(n0 + (e0 >> 5)) * DM + (e0 & 31);
    const ushort* gB1 = Wt + (size_t)(n0 + (e1 >> 5)) * DM + (e1 & 31);

    f32x4 acc[4][4];
#pragma unroll
    for (int i = 0; i < 4; ++i)
#pragma unroll
        for (int j = 0; j < 4; ++j) { acc[i][j][0] = 0.f; acc[i][j][1] = 0.f; acc[i][j][2] = 0.f; acc[i][j][3] = 0.f; }

    gl_lds16(gA0, &Asf[0][e0]);
    gl_lds16(gA1, &Asf[0][e1]);
    gl_lds16(gB0, &Bsf[0][e0]);
    gl_lds16(gB1, &Bsf[0][e1]);
    wait_vm0_barrier();

    int cur = 0;
    for (int kt = 0; kt < 31; ++kt) {
        const int kn = (kt + 1) * 32;
        gl_lds16(gA0 + kn, &Asf[cur ^ 1][e0]);
        gl_lds16(gA1 + kn, &Asf[cur ^ 1][e1]);
        gl_lds16(gB0 + kn, &Bsf[cur ^ 1][e0]);
        gl_lds16(gB1 + kn, &Bsf[cur ^ 1][e1]);

        bf16x8 af[4], bfr[4];
#pragma unroll
        for (int tm = 0; tm < 4; ++tm) af[tm] = *(const bf16x8*)&Asf[cur][(wm + tm * 16 + L) * 32 + quad * 8];
#pragma unroll
        for (int tn = 0; tn < 4; ++tn) bfr[tn] = *(const bf16x8*)&Bsf[cur][(wn + tn * 16 + L) * 32 + quad * 8];
#pragma unroll
        for (int tm = 0; tm < 4; ++tm)
#pragma unroll
            for (int tn = 0; tn < 4; ++tn)
                acc[tm][tn] = MFMA16(af[tm], bfr[tn], acc[tm][tn]);

        wait_vm0_barrier();
        cur ^= 1;
    }
    {
        bf16x8 af[4], bfr[4];
#pragma unroll
        for (int tm = 0; tm < 4; ++tm) af[tm] = *(const bf16x8*)&Asf[cur][(wm + tm * 16 + L) * 32 + quad * 8];
#pragma unroll
        for (int tn = 0; tn < 4; ++tn) bfr[tn] = *(const bf16x8*)&Bsf[cur][(wn + tn * 16 + L) * 32 + quad * 8];
#pragma unroll
        for (int tm = 0; tm < 4; ++tm)
#pragma unroll
            for (int tn = 0; tn < 4; ++tn)
                acc[tm][tn] = MFMA16(af[tm], bfr[tn], acc[tm][tn]);
    }

#pragma unroll
    for (int tm = 0; tm < 4; ++tm)
#pragma unroll
        for (int tn = 0; tn < 4; ++tn)
#pragma unroll
            for (int r = 0; r < 4; ++r) {
                const int mm = m0 + wm + tm * 16 + quad * 4 + r;
                const int n = n0 + wn + tn * 16 + L;
                const int b = mm >> 11, s = mm & 2047;
                const int h = n >> 6, d = n & 63;
                const size_t o = vmode
                    ? ((size_t)(b * HH + h) * DKV + d) * SS + s
                    : ((size_t)(b * HH + h) * SS + s) * DKV + d;
                Out[o] = f2bf(acc[tm][tn][r] * scale);
            }
}

// =====================================================================
// MFMA flash attention.  Changes vs round-3 (proven 159us): V is NOT
// LDS-staged — PV B-fragments load directly from global (per-XCD V set
// is 2MB, L2-resident; loads issued before QK^T for latency cover).
// LDS 27.6KB -> 18.4KB.
// =====================================================================
__global__ __launch_bounds__(256) void attn_mfma(
    const ushort* __restrict__ Q, const ushort* __restrict__ K,
    const ushort* __restrict__ Vt, const unsigned int* __restrict__ pm,
    ushort* __restrict__ Xo)
{
    __shared__ __align__(16) ushort Ks[64][72];
    __shared__ __align__(16) ushort Ps[64][72];

    const int tid = threadIdx.x;
    const int lane = tid & 63, wv = tid >> 6;
    const int quad = lane >> 4, L = lane & 15;
    const int bid = blockIdx.y * gridDim.x + blockIdx.x;
    const int swz = (bid & 7) * 256 + (bid >> 3);
    const int bh = swz >> 5, b = bh >> 4, h = bh & 15;
    const int q0 = (swz & 31) * 64;

    const ushort* qp = &Q[((size_t)bh * SS + q0 + wv * 16 + L) * DKV + quad * 8];
    const bf16x8 aq0 = *(const bf16x8*)qp;
    const bf16x8 aq1 = *(const bf16x8*)(qp + 32);

    f32x4 O[4];
    float lacc[4];
#pragma unroll
    for (int t = 0; t < 4; ++t) { O[t][0] = 0.f; O[t][1] = 0.f; O[t][2] = 0.f; O[t][3] = 0.f; }
#pragma unroll
    for (int r = 0; r < 4; ++r) lacc[r] = 0.f;

    const int sr = tid >> 2, sg = tid & 3;
    const ushort* kbase = &K[((size_t)bh * SS + sr) * DKV + sg * 16];
    // per-thread V row pointers (row d = t*16+L), advance 64/tile
    const ushort* vb[4];
#pragma unroll
    for (int t = 0; t < 4; ++t)
        vb[t] = &Vt[((size_t)bh * DKV + t * 16 + L) * SS + quad * 8];
    const unsigned int* pmr[4];
#pragma unroll
    for (int r = 0; r < 4; ++r)
        pmr[r] = pm + ((size_t)b * SS + q0 + wv * 16 + quad * 4 + r) * 64;

    for (int kt = 0; kt < 32; ++kt) {
        __syncthreads();   // all waves done reading Ks before restage
        *(uint4*)&Ks[sr][sg * 16]     = *(const uint4*)kbase;
        *(uint4*)&Ks[sr][sg * 16 + 8] = *(const uint4*)(kbase + 8);
        kbase += 64 * DKV;

        // V fragments direct from global — issued here, consumed in PV
        bf16x8 vf0[4], vf1[4];
#pragma unroll
        for (int t = 0; t < 4; ++t) {
            vf0[t] = *(const bf16x8*)(vb[t]);
            vf1[t] = *(const bf16x8*)(vb[t] + 32);
            vb[t] += 64;
        }

        uint2 mw[4];
#pragma unroll
        for (int r = 0; r < 4; ++r) mw[r] = *(const uint2*)(pmr[r] + 2 * kt);

        __syncthreads();

        f32x4 sc[4];
        __builtin_amdgcn_s_setprio(1);
#pragma unroll
        for (int t = 0; t < 4; ++t) {
            bf16x8 b0 = *(const bf16x8*)&Ks[t * 16 + L][quad * 8];
            bf16x8 b1 = *(const bf16x8*)&Ks[t * 16 + L][32 + quad * 8];
            f32x4 c; c[0] = 0.f; c[1] = 0.f; c[2] = 0.f; c[3] = 0.f;
            c = MFMA16(aq0, b0, c);
            c = MFMA16(aq1, b1, c);
            sc[t] = c;
        }
        __builtin_amdgcn_s_setprio(0);

#pragma unroll
        for (int r = 0; r < 4; ++r) {
            const unsigned mx = mw[r].x, my = mw[r].y;
#pragma unroll
            for (int t = 0; t < 4; ++t) {
                const float s = fminf(sc[t][r], 30.f);
                const float e = __expf(s);
                const unsigned wsel = (t & 2) ? my : mx;
                const float p = ((wsel >> ((t & 1) * 16 + L)) & 1u) ? e : 0.f;
                lacc[r] += p;
                Ps[wv * 16 + quad * 4 + r][t * 16 + L] = f2bf_t(p);
            }
        }

        bf16x8 ap0 = *(const bf16x8*)&Ps[wv * 16 + L][quad * 8];
        bf16x8 ap1 = *(const bf16x8*)&Ps[wv * 16 + L][32 + quad * 8];
        __builtin_amdgcn_s_setprio(1);
#pragma unroll
        for (int t = 0; t < 4; ++t) {
            O[t] = MFMA16(ap0, vf0[t], O[t]);
            O[t] = MFMA16(ap1, vf1[t], O[t]);
        }
        __builtin_amdgcn_s_setprio(0);
    }

    float inv[4];
#pragma unroll
    for (int r = 0; r < 4; ++r) {
        float l = lacc[r];
#pragma unroll
        for (int off = 1; off < 16; off <<= 1) l += __shfl_xor(l, off, 64);
        inv[r] = 1.f / l;
    }
#pragma unroll
    for (int t = 0; t < 4; ++t)
#pragma unroll
        for (int r = 0; r < 4; ++r) {
            const int qg = q0 + wv * 16 + quad * 4 + r;
            Xo[((size_t)b * SS + qg) * DM + h * DKV + t * 16 + L] = f2bf(O[t][r] * inv[r]);
        }
}

// =====================================================================
// Output projection (round-3 proven body): X @ Wt2 + query -> fp32 OutF.
// =====================================================================
__global__ __launch_bounds__(256) void oproj_mfma(
    const ushort* __restrict__ Xin, const ushort* __restrict__ Wt,
    const void* __restrict__ Qres, float* __restrict__ OutF)
{
    __shared__ __align__(16) ushort Asf[2][4096];
    __shared__ __align__(16) ushort Bsf[2][4096];

    const int mq = sniff_local(Qres, 4096);

    const int tid = threadIdx.x;
    const int lane = tid & 63, wv = tid >> 6;
    const int quad = lane >> 4, L = lane & 15;
    const int bid = blockIdx.y * gridDim.x + blockIdx.x;
    const int swz = (bid & 7) * 64 + (bid >> 3);
    const int m0 = (swz >> 3) * 128, n0 = (swz & 7) * 128;
    const int wm = (wv >> 1) * 64, wn = (wv & 1) * 64;

    const int e0 = (wv * 2 + 0) * 512 + lane * 8;
    const int e1 = (wv * 2 + 1) * 512 + lane * 8;
    const ushort* gA0 = Xin + (size_t)(m0 + (e0 >> 5)) * DM + (e0 & 31);
    const ushort* gA1 = Xin + (size_t)(m0 + (e1 >> 5)) * DM + (e1 & 31);
    const ushort* gB0 = Wt  + (size_t)(n0 + (e0 >> 5)) * DM + (e0 & 31);
    const ushort* gB1 = Wt  + (size_t)(n0 + (e1 >> 5)) * DM + (e1 & 31);

    f32x4 acc[4][4];
#pragma unroll
    for (int i = 0; i < 4; ++i)
#pragma unroll
        for (int j = 0; j < 4; ++j) { acc[i][j][0] = 0.f; acc[i][j][1] = 0.f; acc[i][j][2] = 0.f; acc[i][j][3] = 0.f; }

    gl_lds16(gA0, &Asf[0][e0]);
    gl_lds16(gA1, &Asf[0][e1]);
    gl_lds16(gB0, &Bsf[0][e0]);
    gl_lds16(gB1, &Bsf[0][e1]);
    wait_vm0_barrier();

    int cur = 0;
    for (int kt = 0; kt < 31; ++kt) {
        const int kn = (kt + 1) * 32;
        gl_lds16(gA0 + kn, &Asf[cur ^ 1][e0]);
        gl_lds16(gA1 + kn, &Asf[cur ^ 1][e1]);
        gl_lds16(gB0 + kn, &Bsf[cur ^ 1][e0]);
        gl_lds16(gB1 + kn, &Bsf[cur ^ 1][e1]);

        bf16x8 af[4], bfr[4];
#pragma unroll
        for (int tm = 0; tm < 4; ++tm) af[tm] = *(const bf16x8*)&Asf[cur][(wm + tm * 16 + L) * 32 + quad * 8];
#pragma unroll
        for (int tn = 0; tn < 4; ++tn) bfr[tn] = *(const bf16x8*)&Bsf[cur][(wn + tn * 16 + L) * 32 + quad * 8];
#pragma unroll
        for (int tm = 0; tm < 4; ++tm)
#pragma unroll
            for (int tn = 0; tn < 4; ++tn)
                acc[tm][tn] = MFMA16(af[tm], bfr[tn], acc[tm][tn]);

        wait_vm0_barrier();
        cur ^= 1;
    }
    {
        bf16x8 af[4], bfr[4];
#pragma unroll
        for (int tm = 0; tm < 4; ++tm) af[tm] = *(const bf16x8*)&Asf[cur][(wm + tm * 16 + L) * 32 + quad * 8];
#pragma unroll
        for (int tn = 0; tn < 4; ++tn) bfr[tn] = *(const bf16x8*)&Bsf[cur][(wn + tn * 16 + L) * 32 + quad * 8];
#pragma unroll
        for (int tm = 0; tm < 4; ++tm)
#pragma unroll
            for (int tn = 0; tn < 4; ++tn)
                acc[tm][tn] = MFMA16(af[tm], bfr[tn], acc[tm][tn]);
    }

#pragma unroll
    for (int tm = 0; tm < 4; ++tm)
#pragma unroll
        for (int tn = 0; tn < 4; ++tn)
#pragma unroll
            for (int r = 0; r < 4; ++r) {
                const int mm = m0 + wm + tm * 16 + quad * 4 + r;
                const int n = n0 + wn + tn * 16 + L;
                const size_t idx = (size_t)mm * DM + n;
                OutF[idx] = acc[tm][tn][r] + loadS(Qres, mq, idx);
            }
}

// =====================================================================
// LayerNorm: reads OutF (fp32, ws), writes final d_out. 1 row per wave.
// =====================================================================
__global__ __launch_bounds__(256) void ln_k(
    const float* __restrict__ In, float* __restrict__ Out,
    const void* __restrict__ G, const void* __restrict__ Bt)
{
    const int mg = sniff_local(G, 1024);
    const int mb = sniff_local(Bt, 1024);

    const int tid = threadIdx.x, wv = tid >> 6, lane = tid & 63;
    const int row = blockIdx.x * 4 + wv;
    const size_t base = (size_t)row * DM + lane * 16;

    float v[16];
    float s = 0.f, q = 0.f;
#pragma unroll
    for (int j = 0; j < 16; j += 4) {
        float4 t = *(const float4*)&In[base + j];
        v[j] = t.x; v[j+1] = t.y; v[j+2] = t.z; v[j+3] = t.w;
        s += t.x + t.y + t.z + t.w;
        q += t.x*t.x + t.y*t.y + t.z*t.z + t.w*t.w;
    }
#pragma unroll
    for (int off = 1; off < 64; off <<= 1) {
        s += __shfl_xor(s, off, 64);
        q += __shfl_xor(q, off, 64);
    }
    const float mu = s * (1.f / 1024.f);
    const float var = q * (1.f / 1024.f) - mu * mu;
    const float inv = rsqrtf(var + LNEPS);

    float gj[16], bj[16];
#pragma unroll
    for (int j = 0; j < 16; j += 4) {
        load4m(G,  mg, (size_t)lane * 16 + j, gj + j);
        load4m(Bt, mb, (size_t)lane * 16 + j, bj + j);
    }
#pragma unroll
    for (int j = 0; j < 16; j += 4) {
        float4 o;
        o.x = (v[j]   - mu) * inv * gj[j]   + bj[j];
        o.y = (v[j+1] - mu) * inv * gj[j+1] + bj[j+1];
        o.z = (v[j+2] - mu) * inv * gj[j+2] + bj[j+2];
        o.w = (v[j+3] - mu) * inv * gj[j+3] + bj[j+3];
        *(float4*)&Out[base + j] = o;
    }
}

// =====================================================================
extern "C" void kernel_launch(void* const* d_in, const int* in_sizes, int n_in,
                              void* d_out, int out_size, void* d_ws, size_t ws_size,
                              hipStream_t stream)
{
    const void* query = d_in[0];
    const void* key_i = d_in[1];
    const void* value = d_in[2];
    const int*  mask  = (const int*)d_in[3];
    const void* w_qs  = d_in[4];
    const void* w_ks  = d_in[5];
    const void* w_vs  = d_in[6];
    const void* w_out = d_in[7];
    const void* ln_g  = d_in[8];
    const void* ln_b  = d_in[9];
    float* out = (float*)d_out;

    // ws (64MB): [pad 256B][Qw 16][Kw 16][Vw 16][Xw 16]
    //   Xw hosts Abv during prep/projqv, then Abk, then attn's X output.
    //   OutF (32MB fp32) = Qw+Kw region, live only post-attn.
    // d_out (32MB, final write in ln_k):
    //   pmask@0 (2), Wtq@2, Wtk@4, Wtv@6, Wt2@8 (2 each), Abq@10..26.
    const size_t PE = (size_t)BB * HH * SS * DKV;  // 8,388,608
    ushort* Qw = (ushort*)((char*)d_ws + 256);
    ushort* Kw = Qw + PE;
    ushort* Vw = Kw + PE;   // transposed layout [bh][d][s]
    ushort* Xw = Vw + PE;
    float*  OutF = (float*)Qw;
    unsigned int* pmask = (unsigned int*)d_out;
    ushort* Wtq = (ushort*)((char*)d_out + (2 << 20));
    ushort* Wtk = (ushort*)((char*)d_out + (4 << 20));
    ushort* Wtv = (ushort*)((char*)d_out + (6 << 20));
    ushort* Wt2 = (ushort*)((char*)d_out + (8 << 20));
    ushort* Abq = (ushort*)((char*)d_out + (10 << 20));
    ushort* Abv = Xw;
    ushort* Abk = Xw;   // reused after projqv consumes Abv

    prep<<<7168, 256, 0, stream>>>(mask, pmask, w_qs, w_ks, w_vs, w_out,
                                   Wtq, Wtk, Wtv, Wt2, query, value, Abq, Abv);

    ProjArgs pqv;
    pqv.A[0] = Abq; pqv.Wt[0] = Wtq; pqv.Out[0] = Qw; pqv.vmode[0] = 0; pqv.scale[0] = 0.125f;
    pqv.A[1] = Abv; pqv.Wt[1] = Wtv; pqv.Out[1] = Vw; pqv.vmode[1] = 1; pqv.scale[1] = 1.0f;
    proj_mfma<<<dim3(8, 64, 2), 256, 0, stream>>>(pqv);

    aconv_k<<<2048, 256, 0, stream>>>(key_i, Abk);

    ProjArgs pk;
    pk.A[0] = Abk; pk.Wt[0] = Wtk; pk.Out[0] = Kw; pk.vmode[0] = 0; pk.scale[0] = 1.0f;
    pk.A[1] = Abk; pk.Wt[1] = Wtk; pk.Out[1] = Kw; pk.vmode[1] = 0; pk.scale[1] = 1.0f;
    proj_mfma<<<dim3(8, 64, 1), 256, 0, stream>>>(pk);

    attn_mfma<<<dim3(32, 64), 256, 0, stream>>>(Qw, Kw, Vw, pmask, Xw);

    oproj_mfma<<<dim3(8, 64), 256, 0, stream>>>(Xw, Wt2, query, OutF);

    ln_k<<<2048, 256, 0, stream>>>(OutF, out, ln_g, ln_b);
}

// Round 7
// 557.516 us; speedup vs baseline: 1.2410x; 1.2410x over previous
//
#include <hip/hip_runtime.h>

#define BB   4
#define SS   2048
#define HH   16
#define DM   1024
#define DKV  64
#define LNEPS 1e-6f

#define MD_BF16 0
#define MD_F32  1
#define MD_F16  2

typedef __attribute__((ext_vector_type(8))) short bf16x8;
typedef __attribute__((ext_vector_type(4))) float f32x4;
#define MFMA16(a,b,c) __builtin_amdgcn_mfma_f32_16x16x32_bf16(a,b,c,0,0,0)

// async global->LDS DMA, 16B per lane (dest = wave-uniform base + lane*16)
__device__ __forceinline__ void gl_lds16(const ushort* g, ushort* l) {
    __builtin_amdgcn_global_load_lds(
        (const __attribute__((address_space(1))) void*)g,
        (__attribute__((address_space(3))) void*)l, 16, 0, 0);
}
__device__ __forceinline__ void wait_vm0_barrier() {
    asm volatile("s_waitcnt vmcnt(0)" ::: "memory");
    __builtin_amdgcn_s_barrier();
}

// ---------- dtype helpers ----------
__device__ __forceinline__ float2 unpack2(unsigned int u) {
    union { unsigned int i; float f; } a, b;
    a.i = u << 16;
    b.i = u & 0xffff0000u;
    return make_float2(a.f, b.f);
}
__device__ __forceinline__ unsigned short f2bf(float f) {   // RNE
    union { float f; unsigned int i; } c; c.f = f;
    unsigned int u = c.i;
    unsigned int r = u + 0x7fffu + ((u >> 16) & 1u);
    return (unsigned short)(r >> 16);
}
__device__ __forceinline__ unsigned short f2bf_t(float f) { // truncate
    union { float f; unsigned int i; } c; c.f = f;
    return (unsigned short)(c.i >> 16);
}
__device__ __forceinline__ float h2f(unsigned int bits16) {
    unsigned short s = (unsigned short)bits16;
    _Float16 x;
    __builtin_memcpy(&x, &s, 2);
    return (float)x;
}
__device__ __forceinline__ void load4m(const void* p, int mode, size_t e0, float* o) {
    if (mode == MD_F32) {
        float4 v = *(const float4*)((const float*)p + e0);
        o[0] = v.x; o[1] = v.y; o[2] = v.z; o[3] = v.w;
    } else {
        uint2 u = *(const uint2*)((const ushort*)p + e0);
        if (mode == MD_BF16) {
            float2 a = unpack2(u.x), b = unpack2(u.y);
            o[0] = a.x; o[1] = a.y; o[2] = b.x; o[3] = b.y;
        } else {
            o[0] = h2f(u.x & 0xFFFFu); o[1] = h2f(u.x >> 16);
            o[2] = h2f(u.y & 0xFFFFu); o[3] = h2f(u.y >> 16);
        }
    }
}
__device__ __forceinline__ float loadS(const void* p, int mode, size_t i) {
    if (mode == MD_F32) return ((const float*)p)[i];
    unsigned short u = ((const ushort*)p)[i];
    if (mode == MD_BF16) { union { unsigned i; float f; } c; c.i = (unsigned)u << 16; return c.f; }
    return h2f(u);
}

// raw 16-elem load + convert (same rounding chain as all prior rounds)
__device__ __forceinline__ void loadAraw(const void* p, int m, size_t e, uint4* r) {
    if (m == MD_F32) {
        const float* f = (const float*)p + e;
        r[0] = *(const uint4*)(f);
        r[1] = *(const uint4*)(f + 4);
        r[2] = *(const uint4*)(f + 8);
        r[3] = *(const uint4*)(f + 12);
    } else {
        const ushort* s = (const ushort*)p + e;
        r[0] = *(const uint4*)s;
        r[1] = *(const uint4*)(s + 8);
    }
}
__device__ __forceinline__ void cvtA16(const uint4* r, int m, uint4* o2) {
    union { ushort u[16]; uint4 v[2]; } o;
    if (m == MD_F32) {
        const float* f = (const float*)r;
#pragma unroll
        for (int j = 0; j < 16; ++j) o.u[j] = f2bf(f[j]);
    } else if (m == MD_BF16) {
        o.v[0] = r[0]; o.v[1] = r[1];
    } else {
        const ushort* s = (const ushort*)r;
#pragma unroll
        for (int j = 0; j < 16; ++j) o.u[j] = f2bf(h2f(s[j]));
    }
    o2[0] = o.v[0]; o2[1] = o.v[1];
}

// per-block dtype sniff (same function of same bytes everywhere)
__device__ __forceinline__ int sniff_local(const void* p_, int nhalf) {
    __shared__ int cE, cO;
    const ushort* p = (const ushort*)p_;
    if (threadIdx.x == 0) { cE = 0; cO = 0; }
    __syncthreads();
    int e = 0, o = 0;
    for (int i = threadIdx.x; i < nhalf; i += 256) {
        unsigned ex = (p[i] >> 7) & 0xFFu;
        int hit = (ex < 100u || ex == 0xFFu) ? 1 : 0;
        if (i & 1) o += hit; else e += hit;
    }
    atomicAdd(&cE, e);
    atomicAdd(&cO, o);
    __syncthreads();
    const int total = cE + cO;
    return (total < 48) ? MD_BF16 : ((cO * 4 < cE) ? MD_F32 : MD_F16);
}

// ---------- shared bodies ----------
__device__ __forceinline__ void wtrans_body(
    const void* __restrict__ W, ushort* __restrict__ Wt, int m, int sub)
{
    __shared__ ushort T[64][68];
    const int tid = threadIdx.x;
    const int n0 = (sub & 15) * 64, k0 = (sub >> 4) * 64;

    const int r = tid >> 2, c = (tid & 3) * 16;
    float t[4];
#pragma unroll
    for (int j = 0; j < 4; ++j) {
        load4m(W, m, (size_t)(k0 + r) * DM + n0 + c + 4 * j, t);
#pragma unroll
        for (int i = 0; i < 4; ++i) T[r][c + 4 * j + i] = f2bf(t[i]);
    }
    __syncthreads();

    const int rn = tid >> 2, ck = (tid & 3) * 16;
    union { ushort u[8]; uint4 v; } p0, p1;
#pragma unroll
    for (int j = 0; j < 8; ++j) { p0.u[j] = T[ck + j][rn]; p1.u[j] = T[ck + 8 + j][rn]; }
    ushort* op = &Wt[(size_t)(n0 + rn) * DM + k0 + ck];
    *(uint4*)op = p0.v;
    *(uint4*)(op + 8) = p1.v;
}

__device__ __forceinline__ void aconv_body(
    const void* __restrict__ A, ushort* __restrict__ Ab, int bidl)
{
    const int m = sniff_local(A, 4096);
    const size_t e0 = ((size_t)bidl * 256 + threadIdx.x) * 16;
    uint4 r[4], o[2];
    loadAraw(A, m, e0, r);
    cvtA16(r, m, o);
    *(uint4*)&Ab[e0]     = o[0];
    *(uint4*)&Ab[e0 + 8] = o[1];
}

// =====================================================================
// prep (one launch, 7168 blocks):
//   [0,2048)    mask bit-pack -> pm (2MB)
//   [2048,3072) 4x weight transpose (w_qs,w_ks,w_vs,w_out -> Wt*)
//   [3072,5120) aconv(query) -> Abq
//   [5120,7168) aconv(value) -> Abv
// =====================================================================
__global__ __launch_bounds__(256) void prep(
    const int* __restrict__ mask, unsigned int* __restrict__ pm,
    const void* __restrict__ w_qs, const void* __restrict__ w_ks,
    const void* __restrict__ w_vs, const void* __restrict__ w_out,
    ushort* __restrict__ Wtq, ushort* __restrict__ Wtk,
    ushort* __restrict__ Wtv, ushort* __restrict__ Wt2,
    const void* __restrict__ query, const void* __restrict__ value,
    ushort* __restrict__ Abq, ushort* __restrict__ Abv)
{
    const int bid = blockIdx.x;
    if (bid < 2048) {
        const int w = bid * 256 + threadIdx.x;
        const int* p = mask + (size_t)w * 32;
        unsigned int bits = 0u;
#pragma unroll
        for (int j = 0; j < 8; ++j) {
            int4 v = *(const int4*)(p + j * 4);
            bits |= (v.x ? 1u : 0u) << (4 * j);
            bits |= (v.y ? 1u : 0u) << (4 * j + 1);
            bits |= (v.z ? 1u : 0u) << (4 * j + 2);
            bits |= (v.w ? 1u : 0u) << (4 * j + 3);
        }
        pm[w] = bits;
    } else if (bid < 3072) {
        const int b2 = bid - 2048;
        const int g = b2 >> 8, sub = b2 & 255;
        const void* W = (g == 0) ? w_qs : (g == 1) ? w_ks : (g == 2) ? w_vs : w_out;
        ushort* Wt = (g == 0) ? Wtq : (g == 1) ? Wtk : (g == 2) ? Wtv : Wt2;
        wtrans_body(W, Wt, sniff_local(W, 4096), sub);
    } else if (bid < 5120) {
        aconv_body(query, Abq, bid - 3072);
    } else {
        aconv_body(value, Abv, bid - 5120);
    }
}

// standalone aconv for key (runs after projqv frees the Abv/Xw region)
__global__ __launch_bounds__(256) void aconv_k(
    const void* __restrict__ A, ushort* __restrict__ Ab)
{
    aconv_body(A, Ab, blockIdx.x);
}

// =====================================================================
// MFMA projection GEMM: round-3 proven dbuf structure, BK=64.
// 128x128 tile, 16 K-steps of 64; 32 MFMA cover per staging wait.
// LDS 64KB (2 blocks/CU — grid is 512/z = 2/CU anyway).
// =====================================================================
struct ProjArgs {
    const ushort* A[2]; const ushort* Wt[2]; ushort* Out[2];
    int vmode[2]; float scale[2];
};

__global__ __launch_bounds__(256) void proj_mfma(ProjArgs pa)
{
    __shared__ __align__(16) ushort Asf[2][128 * 64];
    __shared__ __align__(16) ushort Bsf[2][128 * 64];

    const int z = blockIdx.z;
    const ushort* A  = pa.A[z];
    const ushort* Wt = pa.Wt[z];
    ushort* Out = pa.Out[z];
    const int vmode = pa.vmode[z];
    const float scale = pa.scale[z];

    const int tid = threadIdx.x;
    const int lane = tid & 63, wv = tid >> 6;
    const int quad = lane >> 4, L = lane & 15;
    const int bid = blockIdx.y * gridDim.x + blockIdx.x;   // 512 per z
    const int swz = (bid & 7) * 64 + (bid >> 3);           // XCD-chunked
    const int m0 = (swz >> 3) * 128, n0 = (swz & 7) * 128;
    const int wm = (wv >> 1) * 64, wn = (wv & 1) * 64;

    // staging: 16 segments of 512 elems (1KB/wave-call); 4 per wave
    int e_[4];
    const ushort* gA_[4];
    const ushort* gB_[4];
#pragma unroll
    for (int c = 0; c < 4; ++c) {
        e_[c] = (wv * 4 + c) * 512 + lane * 8;
        gA_[c] = A  + (size_t)(m0 + (e_[c] >> 6)) * DM + (e_[c] & 63);
        gB_[c] = Wt + (size_t)(n0 + (e_[c] >> 6)) * DM + (e_[c] & 63);
    }

    f32x4 acc[4][4];
#pragma unroll
    for (int i = 0; i < 4; ++i)
#pragma unroll
        for (int j = 0; j < 4; ++j) { acc[i][j][0] = 0.f; acc[i][j][1] = 0.f; acc[i][j][2] = 0.f; acc[i][j][3] = 0.f; }

#define STAGE_P(BUF, KOFF)                                                     \
    { _Pragma("unroll") for (int c = 0; c < 4; ++c) {                          \
          gl_lds16(gA_[c] + (KOFF), &Asf[BUF][e_[c]]);                         \
          gl_lds16(gB_[c] + (KOFF), &Bsf[BUF][e_[c]]); } }

#define MFMA_P(BUF)                                                            \
    { _Pragma("unroll") for (int h = 0; h < 2; ++h) {                          \
          bf16x8 af[4], bfr[4];                                                \
          _Pragma("unroll") for (int tm = 0; tm < 4; ++tm)                     \
              af[tm] = *(const bf16x8*)&Asf[BUF][(wm + tm * 16 + L) * 64 + h * 32 + quad * 8]; \
          _Pragma("unroll") for (int tn = 0; tn < 4; ++tn)                     \
              bfr[tn] = *(const bf16x8*)&Bsf[BUF][(wn + tn * 16 + L) * 64 + h * 32 + quad * 8]; \
          _Pragma("unroll") for (int tm = 0; tm < 4; ++tm)                     \
          _Pragma("unroll") for (int tn = 0; tn < 4; ++tn)                     \
              acc[tm][tn] = MFMA16(af[tm], bfr[tn], acc[tm][tn]); } }

    STAGE_P(0, 0)
    wait_vm0_barrier();

    int cur = 0;
    for (int kt = 0; kt < 15; ++kt) {
        STAGE_P(cur ^ 1, (kt + 1) * 64)   // prefetch flies across MFMA
        MFMA_P(cur)
        wait_vm0_barrier();
        cur ^= 1;
    }
    MFMA_P(cur)

#pragma unroll
    for (int tm = 0; tm < 4; ++tm)
#pragma unroll
        for (int tn = 0; tn < 4; ++tn)
#pragma unroll
            for (int r = 0; r < 4; ++r) {
                const int mm = m0 + wm + tm * 16 + quad * 4 + r;
                const int n = n0 + wn + tn * 16 + L;
                const int b = mm >> 11, s = mm & 2047;
                const int h = n >> 6, d = n & 63;
                const size_t o = vmode
                    ? ((size_t)(b * HH + h) * DKV + d) * SS + s
                    : ((size_t)(b * HH + h) * SS + s) * DKV + d;
                Out[o] = f2bf(acc[tm][tn][r] * scale);
            }
}

// =====================================================================
// MFMA flash attention — exact round-3 body (proven 159us):
// K/V/P LDS-staged, packed bitmask, XCD-chunked swizzle, setprio.
// =====================================================================
__global__ __launch_bounds__(256) void attn_mfma(
    const ushort* __restrict__ Q, const ushort* __restrict__ K,
    const ushort* __restrict__ Vt, const unsigned int* __restrict__ pm,
    ushort* __restrict__ Xo)
{
    __shared__ __align__(16) ushort Ks[64][72];
    __shared__ __align__(16) ushort Vs[64][72];
    __shared__ __align__(16) ushort Ps[64][72];

    const int tid = threadIdx.x;
    const int lane = tid & 63, wv = tid >> 6;
    const int quad = lane >> 4, L = lane & 15;
    const int bid = blockIdx.y * gridDim.x + blockIdx.x;
    const int swz = (bid & 7) * 256 + (bid >> 3);
    const int bh = swz >> 5, b = bh >> 4, h = bh & 15;
    const int q0 = (swz & 31) * 64;

    const ushort* qp = &Q[((size_t)bh * SS + q0 + wv * 16 + L) * DKV + quad * 8];
    const bf16x8 aq0 = *(const bf16x8*)qp;
    const bf16x8 aq1 = *(const bf16x8*)(qp + 32);

    f32x4 O[4];
    float lacc[4];
#pragma unroll
    for (int t = 0; t < 4; ++t) { O[t][0] = 0.f; O[t][1] = 0.f; O[t][2] = 0.f; O[t][3] = 0.f; }
#pragma unroll
    for (int r = 0; r < 4; ++r) lacc[r] = 0.f;

    const int sr = tid >> 2, sg = tid & 3;
    const ushort* kbase = &K[((size_t)bh * SS + sr) * DKV + sg * 16];
    const ushort* vbase = &Vt[((size_t)bh * DKV + sr) * SS + sg * 16];
    const unsigned int* pmr[4];
#pragma unroll
    for (int r = 0; r < 4; ++r)
        pmr[r] = pm + ((size_t)b * SS + q0 + wv * 16 + quad * 4 + r) * 64;

    for (int kt = 0; kt < 32; ++kt) {
        __syncthreads();
        *(uint4*)&Ks[sr][sg * 16]     = *(const uint4*)kbase;
        *(uint4*)&Ks[sr][sg * 16 + 8] = *(const uint4*)(kbase + 8);
        *(uint4*)&Vs[sr][sg * 16]     = *(const uint4*)vbase;
        *(uint4*)&Vs[sr][sg * 16 + 8] = *(const uint4*)(vbase + 8);
        kbase += 64 * DKV;
        vbase += 64;

        uint2 mw[4];
#pragma unroll
        for (int r = 0; r < 4; ++r) mw[r] = *(const uint2*)(pmr[r] + 2 * kt);

        __syncthreads();

        f32x4 sc[4];
        __builtin_amdgcn_s_setprio(1);
#pragma unroll
        for (int t = 0; t < 4; ++t) {
            bf16x8 b0 = *(const bf16x8*)&Ks[t * 16 + L][quad * 8];
            bf16x8 b1 = *(const bf16x8*)&Ks[t * 16 + L][32 + quad * 8];
            f32x4 c; c[0] = 0.f; c[1] = 0.f; c[2] = 0.f; c[3] = 0.f;
            c = MFMA16(aq0, b0, c);
            c = MFMA16(aq1, b1, c);
            sc[t] = c;
        }
        __builtin_amdgcn_s_setprio(0);

#pragma unroll
        for (int r = 0; r < 4; ++r) {
            const unsigned mx = mw[r].x, my = mw[r].y;
#pragma unroll
            for (int t = 0; t < 4; ++t) {
                const float s = fminf(sc[t][r], 30.f);
                const float e = __expf(s);
                const unsigned wsel = (t & 2) ? my : mx;
                const float p = ((wsel >> ((t & 1) * 16 + L)) & 1u) ? e : 0.f;
                lacc[r] += p;
                Ps[wv * 16 + quad * 4 + r][t * 16 + L] = f2bf_t(p);
            }
        }

        bf16x8 ap0 = *(const bf16x8*)&Ps[wv * 16 + L][quad * 8];
        bf16x8 ap1 = *(const bf16x8*)&Ps[wv * 16 + L][32 + quad * 8];
        __builtin_amdgcn_s_setprio(1);
#pragma unroll
        for (int t = 0; t < 4; ++t) {
            bf16x8 v0 = *(const bf16x8*)&Vs[t * 16 + L][quad * 8];
            bf16x8 v1 = *(const bf16x8*)&Vs[t * 16 + L][32 + quad * 8];
            O[t] = MFMA16(ap0, v0, O[t]);
            O[t] = MFMA16(ap1, v1, O[t]);
        }
        __builtin_amdgcn_s_setprio(0);
    }

    float inv[4];
#pragma unroll
    for (int r = 0; r < 4; ++r) {
        float l = lacc[r];
#pragma unroll
        for (int off = 1; off < 16; off <<= 1) l += __shfl_xor(l, off, 64);
        inv[r] = 1.f / l;
    }
#pragma unroll
    for (int t = 0; t < 4; ++t)
#pragma unroll
        for (int r = 0; r < 4; ++r) {
            const int qg = q0 + wv * 16 + quad * 4 + r;
            Xo[((size_t)b * SS + qg) * DM + h * DKV + t * 16 + L] = f2bf(O[t][r] * inv[r]);
        }
}

// =====================================================================
// Output projection: same BK=64 dbuf body; X @ Wt2 + query -> fp32 OutF.
// =====================================================================
__global__ __launch_bounds__(256) void oproj_mfma(
    const ushort* __restrict__ Xin, const ushort* __restrict__ Wt,
    const void* __restrict__ Qres, float* __restrict__ OutF)
{
    __shared__ __align__(16) ushort Asf[2][128 * 64];
    __shared__ __align__(16) ushort Bsf[2][128 * 64];

    const int mq = sniff_local(Qres, 4096);

    const int tid = threadIdx.x;
    const int lane = tid & 63, wv = tid >> 6;
    const int quad = lane >> 4, L = lane & 15;
    const int bid = blockIdx.y * gridDim.x + blockIdx.x;
    const int swz = (bid & 7) * 64 + (bid >> 3);
    const int m0 = (swz >> 3) * 128, n0 = (swz & 7) * 128;
    const int wm = (wv >> 1) * 64, wn = (wv & 1) * 64;

    int e_[4];
    const ushort* gA_[4];
    const ushort* gB_[4];
#pragma unroll
    for (int c = 0; c < 4; ++c) {
        e_[c] = (wv * 4 + c) * 512 + lane * 8;
        gA_[c] = Xin + (size_t)(m0 + (e_[c] >> 6)) * DM + (e_[c] & 63);
        gB_[c] = Wt  + (size_t)(n0 + (e_[c] >> 6)) * DM + (e_[c] & 63);
    }

    f32x4 acc[4][4];
#pragma unroll
    for (int i = 0; i < 4; ++i)
#pragma unroll
        for (int j = 0; j < 4; ++j) { acc[i][j][0] = 0.f; acc[i][j][1] = 0.f; acc[i][j][2] = 0.f; acc[i][j][3] = 0.f; }

#define STAGE_O(BUF, KOFF)                                                     \
    { _Pragma("unroll") for (int c = 0; c < 4; ++c) {                          \
          gl_lds16(gA_[c] + (KOFF), &Asf[BUF][e_[c]]);                         \
          gl_lds16(gB_[c] + (KOFF), &Bsf[BUF][e_[c]]); } }

    STAGE_O(0, 0)
    wait_vm0_barrier();

    int cur = 0;
    for (int kt = 0; kt < 15; ++kt) {
        STAGE_O(cur ^ 1, (kt + 1) * 64)
        MFMA_P(cur)
        wait_vm0_barrier();
        cur ^= 1;
    }
    MFMA_P(cur)

#pragma unroll
    for (int tm = 0; tm < 4; ++tm)
#pragma unroll
        for (int tn = 0; tn < 4; ++tn)
#pragma unroll
            for (int r = 0; r < 4; ++r) {
                const int mm = m0 + wm + tm * 16 + quad * 4 + r;
                const int n = n0 + wn + tn * 16 + L;
                const size_t idx = (size_t)mm * DM + n;
                OutF[idx] = acc[tm][tn][r] + loadS(Qres, mq, idx);
            }
}

// =====================================================================
// LayerNorm: reads OutF (fp32, ws), writes final d_out. 1 row per wave.
// =====================================================================
__global__ __launch_bounds__(256) void ln_k(
    const float* __restrict__ In, float* __restrict__ Out,
    const void* __restrict__ G, const void* __restrict__ Bt)
{
    const int mg = sniff_local(G, 1024);
    const int mb = sniff_local(Bt, 1024);

    const int tid = threadIdx.x, wv = tid >> 6, lane = tid & 63;
    const int row = blockIdx.x * 4 + wv;
    const size_t base = (size_t)row * DM + lane * 16;

    float v[16];
    float s = 0.f, q = 0.f;
#pragma unroll
    for (int j = 0; j < 16; j += 4) {
        float4 t = *(const float4*)&In[base + j];
        v[j] = t.x; v[j+1] = t.y; v[j+2] = t.z; v[j+3] = t.w;
        s += t.x + t.y + t.z + t.w;
        q += t.x*t.x + t.y*t.y + t.z*t.z + t.w*t.w;
    }
#pragma unroll
    for (int off = 1; off < 64; off <<= 1) {
        s += __shfl_xor(s, off, 64);
        q += __shfl_xor(q, off, 64);
    }
    const float mu = s * (1.f / 1024.f);
    const float var = q * (1.f / 1024.f) - mu * mu;
    const float inv = rsqrtf(var + LNEPS);

    float gj[16], bj[16];
#pragma unroll
    for (int j = 0; j < 16; j += 4) {
        load4m(G,  mg, (size_t)lane * 16 + j, gj + j);
        load4m(Bt, mb, (size_t)lane * 16 + j, bj + j);
    }
#pragma unroll
    for (int j = 0; j < 16; j += 4) {
        float4 o;
        o.x = (v[j]   - mu) * inv * gj[j]   + bj[j];
        o.y = (v[j+1] - mu) * inv * gj[j+1] + bj[j+1];
        o.z = (v[j+2] - mu) * inv * gj[j+2] + bj[j+2];
        o.w = (v[j+3] - mu) * inv * gj[j+3] + bj[j+3];
        *(float4*)&Out[base + j] = o;
    }
}

// =====================================================================
extern "C" void kernel_launch(void* const* d_in, const int* in_sizes, int n_in,
                              void* d_out, int out_size, void* d_ws, size_t ws_size,
                              hipStream_t stream)
{
    const void* query = d_in[0];
    const void* key_i = d_in[1];
    const void* value = d_in[2];
    const int*  mask  = (const int*)d_in[3];
    const void* w_qs  = d_in[4];
    const void* w_ks  = d_in[5];
    const void* w_vs  = d_in[6];
    const void* w_out = d_in[7];
    const void* ln_g  = d_in[8];
    const void* ln_b  = d_in[9];
    float* out = (float*)d_out;

    // ws (64MB): [pad 256B][Qw 16][Kw 16][Vw 16][Xw 16]
    //   Xw hosts Abv during prep/projqv, then Abk, then attn's X output.
    //   OutF (32MB fp32) = Qw+Kw region, live only post-attn.
    // d_out (32MB, final write in ln_k):
    //   pmask@0 (2), Wtq@2, Wtk@4, Wtv@6, Wt2@8 (2 each), Abq@10..26.
    const size_t PE = (size_t)BB * HH * SS * DKV;  // 8,388,608
    ushort* Qw = (ushort*)((char*)d_ws + 256);
    ushort* Kw = Qw + PE;
    ushort* Vw = Kw + PE;   // transposed layout [bh][d][s]
    ushort* Xw = Vw + PE;
    float*  OutF = (float*)Qw;
    unsigned int* pmask = (unsigned int*)d_out;
    ushort* Wtq = (ushort*)((char*)d_out + (2 << 20));
    ushort* Wtk = (ushort*)((char*)d_out + (4 << 20));
    ushort* Wtv = (ushort*)((char*)d_out + (6 << 20));
    ushort* Wt2 = (ushort*)((char*)d_out + (8 << 20));
    ushort* Abq = (ushort*)((char*)d_out + (10 << 20));
    ushort* Abv = Xw;
    ushort* Abk = Xw;   // reused after projqv consumes Abv

    prep<<<7168, 256, 0, stream>>>(mask, pmask, w_qs, w_ks, w_vs, w_out,
                                   Wtq, Wtk, Wtv, Wt2, query, value, Abq, Abv);

    ProjArgs pqv;
    pqv.A[0] = Abq; pqv.Wt[0] = Wtq; pqv.Out[0] = Qw; pqv.vmode[0] = 0; pqv.scale[0] = 0.125f;
    pqv.A[1] = Abv; pqv.Wt[1] = Wtv; pqv.Out[1] = Vw; pqv.vmode[1] = 1; pqv.scale[1] = 1.0f;
    proj_mfma<<<dim3(8, 64, 2), 256, 0, stream>>>(pqv);

    aconv_k<<<2048, 256, 0, stream>>>(key_i, Abk);

    ProjArgs pk;
    pk.A[0] = Abk; pk.Wt[0] = Wtk; pk.Out[0] = Kw; pk.vmode[0] = 0; pk.scale[0] = 1.0f;
    pk.A[1] = Abk; pk.Wt[1] = Wtk; pk.Out[1] = Kw; pk.vmode[1] = 0; pk.scale[1] = 1.0f;
    proj_mfma<<<dim3(8, 64, 1), 256, 0, stream>>>(pk);

    attn_mfma<<<dim3(32, 64), 256, 0, stream>>>(Qw, Kw, Vw, pmask, Xw);

    oproj_mfma<<<dim3(8, 64), 256, 0, stream>>>(Xw, Wt2, query, OutF);

    ln_k<<<2048, 256, 0, stream>>>(OutF, out, ln_g, ln_b);
}

// Round 9
// 542.136 us; speedup vs baseline: 1.2762x; 1.0284x over previous
//
#include <hip/hip_runtime.h>

#define BB   4
#define SS   2048
#define HH   16
#define DM   1024
#define DKV  64
#define LNEPS 1e-6f

#define MD_BF16 0
#define MD_F32  1
#define MD_F16  2

typedef __attribute__((ext_vector_type(8))) short bf16x8;
typedef __attribute__((ext_vector_type(4))) float f32x4;
#define MFMA16(a,b,c) __builtin_amdgcn_mfma_f32_16x16x32_bf16(a,b,c,0,0,0)

// async global->LDS DMA, 16B per lane (dest = wave-uniform base + lane*16)
__device__ __forceinline__ void gl_lds16(const ushort* g, ushort* l) {
    __builtin_amdgcn_global_load_lds(
        (const __attribute__((address_space(1))) void*)g,
        (__attribute__((address_space(3))) void*)l, 16, 0, 0);
}
__device__ __forceinline__ void wait_vm0_barrier() {
    asm volatile("s_waitcnt vmcnt(0)" ::: "memory");
    __builtin_amdgcn_s_barrier();
}

// ---------- dtype helpers ----------
__device__ __forceinline__ float2 unpack2(unsigned int u) {
    union { unsigned int i; float f; } a, b;
    a.i = u << 16;
    b.i = u & 0xffff0000u;
    return make_float2(a.f, b.f);
}
__device__ __forceinline__ unsigned short f2bf(float f) {   // RNE
    union { float f; unsigned int i; } c; c.f = f;
    unsigned int u = c.i;
    unsigned int r = u + 0x7fffu + ((u >> 16) & 1u);
    return (unsigned short)(r >> 16);
}
__device__ __forceinline__ unsigned short f2bf_t(float f) { // truncate
    union { float f; unsigned int i; } c; c.f = f;
    return (unsigned short)(c.i >> 16);
}
__device__ __forceinline__ float h2f(unsigned int bits16) {
    unsigned short s = (unsigned short)bits16;
    _Float16 x;
    __builtin_memcpy(&x, &s, 2);
    return (float)x;
}
__device__ __forceinline__ void load4m(const void* p, int mode, size_t e0, float* o) {
    if (mode == MD_F32) {
        float4 v = *(const float4*)((const float*)p + e0);
        o[0] = v.x; o[1] = v.y; o[2] = v.z; o[3] = v.w;
    } else {
        uint2 u = *(const uint2*)((const ushort*)p + e0);
        if (mode == MD_BF16) {
            float2 a = unpack2(u.x), b = unpack2(u.y);
            o[0] = a.x; o[1] = a.y; o[2] = b.x; o[3] = b.y;
        } else {
            o[0] = h2f(u.x & 0xFFFFu); o[1] = h2f(u.x >> 16);
            o[2] = h2f(u.y & 0xFFFFu); o[3] = h2f(u.y >> 16);
        }
    }
}
__device__ __forceinline__ float loadS(const void* p, int mode, size_t i) {
    if (mode == MD_F32) return ((const float*)p)[i];
    unsigned short u = ((const ushort*)p)[i];
    if (mode == MD_BF16) { union { unsigned i; float f; } c; c.i = (unsigned)u << 16; return c.f; }
    return h2f(u);
}

// raw 16-elem load + convert (same rounding chain as all prior rounds)
__device__ __forceinline__ void loadAraw(const void* p, int m, size_t e, uint4* r) {
    if (m == MD_F32) {
        const float* f = (const float*)p + e;
        r[0] = *(const uint4*)(f);
        r[1] = *(const uint4*)(f + 4);
        r[2] = *(const uint4*)(f + 8);
        r[3] = *(const uint4*)(f + 12);
    } else {
        const ushort* s = (const ushort*)p + e;
        r[0] = *(const uint4*)s;
        r[1] = *(const uint4*)(s + 8);
    }
}
__device__ __forceinline__ void cvtA16(const uint4* r, int m, uint4* o2) {
    union { ushort u[16]; uint4 v[2]; } o;
    if (m == MD_F32) {
        const float* f = (const float*)r;
#pragma unroll
        for (int j = 0; j < 16; ++j) o.u[j] = f2bf(f[j]);
    } else if (m == MD_BF16) {
        o.v[0] = r[0]; o.v[1] = r[1];
    } else {
        const ushort* s = (const ushort*)r;
#pragma unroll
        for (int j = 0; j < 16; ++j) o.u[j] = f2bf(h2f(s[j]));
    }
    o2[0] = o.v[0]; o2[1] = o.v[1];
}

// per-block dtype sniff (same function of same bytes everywhere)
__device__ __forceinline__ int sniff_local(const void* p_, int nhalf) {
    __shared__ int cE, cO;
    const ushort* p = (const ushort*)p_;
    if (threadIdx.x == 0) { cE = 0; cO = 0; }
    __syncthreads();
    int e = 0, o = 0;
    for (int i = threadIdx.x; i < nhalf; i += 256) {
        unsigned ex = (p[i] >> 7) & 0xFFu;
        int hit = (ex < 100u || ex == 0xFFu) ? 1 : 0;
        if (i & 1) o += hit; else e += hit;
    }
    atomicAdd(&cE, e);
    atomicAdd(&cO, o);
    __syncthreads();
    const int total = cE + cO;
    return (total < 48) ? MD_BF16 : ((cO * 4 < cE) ? MD_F32 : MD_F16);
}

// ---------- shared bodies ----------
__device__ __forceinline__ void wtrans_body(
    const void* __restrict__ W, ushort* __restrict__ Wt, int m, int sub)
{
    __shared__ ushort T[64][68];
    const int tid = threadIdx.x;
    const int n0 = (sub & 15) * 64, k0 = (sub >> 4) * 64;

    const int r = tid >> 2, c = (tid & 3) * 16;
    float t[4];
#pragma unroll
    for (int j = 0; j < 4; ++j) {
        load4m(W, m, (size_t)(k0 + r) * DM + n0 + c + 4 * j, t);
#pragma unroll
        for (int i = 0; i < 4; ++i) T[r][c + 4 * j + i] = f2bf(t[i]);
    }
    __syncthreads();

    const int rn = tid >> 2, ck = (tid & 3) * 16;
    union { ushort u[8]; uint4 v; } p0, p1;
#pragma unroll
    for (int j = 0; j < 8; ++j) { p0.u[j] = T[ck + j][rn]; p1.u[j] = T[ck + 8 + j][rn]; }
    ushort* op = &Wt[(size_t)(n0 + rn) * DM + k0 + ck];
    *(uint4*)op = p0.v;
    *(uint4*)(op + 8) = p1.v;
}

__device__ __forceinline__ void aconv_body(
    const void* __restrict__ A, ushort* __restrict__ Ab, int bidl)
{
    const int m = sniff_local(A, 4096);
    const size_t e0 = ((size_t)bidl * 256 + threadIdx.x) * 16;
    uint4 r[4], o[2];
    loadAraw(A, m, e0, r);
    cvtA16(r, m, o);
    *(uint4*)&Ab[e0]     = o[0];
    *(uint4*)&Ab[e0 + 8] = o[1];
}

// =====================================================================
// prep (one launch, 7168 blocks):
//   [0,2048)    mask bit-pack -> pm (2MB)
//   [2048,3072) 4x weight transpose (w_qs,w_ks,w_vs,w_out -> Wt*)
//   [3072,5120) aconv(query) -> Abq
//   [5120,7168) aconv(value) -> Abv
// =====================================================================
__global__ __launch_bounds__(256) void prep(
    const int* __restrict__ mask, unsigned int* __restrict__ pm,
    const void* __restrict__ w_qs, const void* __restrict__ w_ks,
    const void* __restrict__ w_vs, const void* __restrict__ w_out,
    ushort* __restrict__ Wtq, ushort* __restrict__ Wtk,
    ushort* __restrict__ Wtv, ushort* __restrict__ Wt2,
    const void* __restrict__ query, const void* __restrict__ value,
    ushort* __restrict__ Abq, ushort* __restrict__ Abv)
{
    const int bid = blockIdx.x;
    if (bid < 2048) {
        const int w = bid * 256 + threadIdx.x;
        const int* p = mask + (size_t)w * 32;
        unsigned int bits = 0u;
#pragma unroll
        for (int j = 0; j < 8; ++j) {
            int4 v = *(const int4*)(p + j * 4);
            bits |= (v.x ? 1u : 0u) << (4 * j);
            bits |= (v.y ? 1u : 0u) << (4 * j + 1);
            bits |= (v.z ? 1u : 0u) << (4 * j + 2);
            bits |= (v.w ? 1u : 0u) << (4 * j + 3);
        }
        pm[w] = bits;
    } else if (bid < 3072) {
        const int b2 = bid - 2048;
        const int g = b2 >> 8, sub = b2 & 255;
        const void* W = (g == 0) ? w_qs : (g == 1) ? w_ks : (g == 2) ? w_vs : w_out;
        ushort* Wt = (g == 0) ? Wtq : (g == 1) ? Wtk : (g == 2) ? Wtv : Wt2;
        wtrans_body(W, Wt, sniff_local(W, 4096), sub);
    } else if (bid < 5120) {
        aconv_body(query, Abq, bid - 3072);
    } else {
        aconv_body(value, Abv, bid - 5120);
    }
}

// standalone aconv for key (runs after projqv frees the Abv/Xw region)
__global__ __launch_bounds__(256) void aconv_k(
    const void* __restrict__ A, ushort* __restrict__ Ab)
{
    aconv_body(A, Ab, blockIdx.x);
}

// =====================================================================
// MFMA projection GEMM — exact round-3 proven body (BK=32, dbuf
// global_load_lds, XCD-chunked swizzle), z-dispatch over 2 GEMMs.
// =====================================================================
struct ProjArgs {
    const ushort* A[2]; const ushort* Wt[2]; ushort* Out[2];
    int vmode[2]; float scale[2];
};

__global__ __launch_bounds__(256) void proj_mfma(ProjArgs pa)
{
    __shared__ __align__(16) ushort Asf[2][4096];
    __shared__ __align__(16) ushort Bsf[2][4096];

    const int z = blockIdx.z;
    const ushort* A  = pa.A[z];
    const ushort* Wt = pa.Wt[z];
    ushort* Out = pa.Out[z];
    const int vmode = pa.vmode[z];
    const float scale = pa.scale[z];

    const int tid = threadIdx.x;
    const int lane = tid & 63, wv = tid >> 6;
    const int quad = lane >> 4, L = lane & 15;
    const int bid = blockIdx.y * gridDim.x + blockIdx.x;   // 512 per z
    const int swz = (bid & 7) * 64 + (bid >> 3);           // XCD-chunked
    const int m0 = (swz >> 3) * 128, n0 = (swz & 7) * 128;
    const int wm = (wv >> 1) * 64, wn = (wv & 1) * 64;

    const int e0 = (wv * 2 + 0) * 512 + lane * 8;
    const int e1 = (wv * 2 + 1) * 512 + lane * 8;
    const ushort* gA0 = A  + (size_t)(m0 + (e0 >> 5)) * DM + (e0 & 31);
    const ushort* gA1 = A  + (size_t)(m0 + (e1 >> 5)) * DM + (e1 & 31);
    const ushort* gB0 = Wt + (size_t)(n0 + (e0 >> 5)) * DM + (e0 & 31);
    const ushort* gB1 = Wt + (size_t)(n0 + (e1 >> 5)) * DM + (e1 & 31);

    f32x4 acc[4][4];
#pragma unroll
    for (int i = 0; i < 4; ++i)
#pragma unroll
        for (int j = 0; j < 4; ++j) { acc[i][j][0] = 0.f; acc[i][j][1] = 0.f; acc[i][j][2] = 0.f; acc[i][j][3] = 0.f; }

    gl_lds16(gA0, &Asf[0][e0]);
    gl_lds16(gA1, &Asf[0][e1]);
    gl_lds16(gB0, &Bsf[0][e0]);
    gl_lds16(gB1, &Bsf[0][e1]);
    wait_vm0_barrier();

    int cur = 0;
    for (int kt = 0; kt < 31; ++kt) {
        const int kn = (kt + 1) * 32;
        gl_lds16(gA0 + kn, &Asf[cur ^ 1][e0]);
        gl_lds16(gA1 + kn, &Asf[cur ^ 1][e1]);
        gl_lds16(gB0 + kn, &Bsf[cur ^ 1][e0]);
        gl_lds16(gB1 + kn, &Bsf[cur ^ 1][e1]);

        bf16x8 af[4], bfr[4];
#pragma unroll
        for (int tm = 0; tm < 4; ++tm) af[tm] = *(const bf16x8*)&Asf[cur][(wm + tm * 16 + L) * 32 + quad * 8];
#pragma unroll
        for (int tn = 0; tn < 4; ++tn) bfr[tn] = *(const bf16x8*)&Bsf[cur][(wn + tn * 16 + L) * 32 + quad * 8];
#pragma unroll
        for (int tm = 0; tm < 4; ++tm)
#pragma unroll
            for (int tn = 0; tn < 4; ++tn)
                acc[tm][tn] = MFMA16(af[tm], bfr[tn], acc[tm][tn]);

        wait_vm0_barrier();
        cur ^= 1;
    }
    {
        bf16x8 af[4], bfr[4];
#pragma unroll
        for (int tm = 0; tm < 4; ++tm) af[tm] = *(const bf16x8*)&Asf[cur][(wm + tm * 16 + L) * 32 + quad * 8];
#pragma unroll
        for (int tn = 0; tn < 4; ++tn) bfr[tn] = *(const bf16x8*)&Bsf[cur][(wn + tn * 16 + L) * 32 + quad * 8];
#pragma unroll
        for (int tm = 0; tm < 4; ++tm)
#pragma unroll
            for (int tn = 0; tn < 4; ++tn)
                acc[tm][tn] = MFMA16(af[tm], bfr[tn], acc[tm][tn]);
    }

#pragma unroll
    for (int tm = 0; tm < 4; ++tm)
#pragma unroll
        for (int tn = 0; tn < 4; ++tn)
#pragma unroll
            for (int r = 0; r < 4; ++r) {
                const int mm = m0 + wm + tm * 16 + quad * 4 + r;
                const int n = n0 + wn + tn * 16 + L;
                const int b = mm >> 11, s = mm & 2047;
                const int h = n >> 6, d = n & 63;
                const size_t o = vmode
                    ? ((size_t)(b * HH + h) * DKV + d) * SS + s
                    : ((size_t)(b * HH + h) * SS + s) * DKV + d;
                Out[o] = f2bf(acc[tm][tn][r] * scale);
            }
}

// =====================================================================
// MFMA flash attention — exact round-3/7 proven body (159-162us):
// K/V/P LDS-staged with inline global->LDS staging, packed bitmask,
// XCD-chunked swizzle, setprio around MFMA clusters.  Only delta:
// mask-word loads hoisted above the first barrier (read-only data,
// identical values, earlier issue).
// =====================================================================
__global__ __launch_bounds__(256) void attn_mfma(
    const ushort* __restrict__ Q, const ushort* __restrict__ K,
    const ushort* __restrict__ Vt, const unsigned int* __restrict__ pm,
    ushort* __restrict__ Xo)
{
    __shared__ __align__(16) ushort Ks[64][72];
    __shared__ __align__(16) ushort Vs[64][72];
    __shared__ __align__(16) ushort Ps[64][72];

    const int tid = threadIdx.x;
    const int lane = tid & 63, wv = tid >> 6;
    const int quad = lane >> 4, L = lane & 15;
    const int bid = blockIdx.y * gridDim.x + blockIdx.x;
    const int swz = (bid & 7) * 256 + (bid >> 3);
    const int bh = swz >> 5, b = bh >> 4, h = bh & 15;
    const int q0 = (swz & 31) * 64;

    const ushort* qp = &Q[((size_t)bh * SS + q0 + wv * 16 + L) * DKV + quad * 8];
    const bf16x8 aq0 = *(const bf16x8*)qp;
    const bf16x8 aq1 = *(const bf16x8*)(qp + 32);

    f32x4 O[4];
    float lacc[4];
#pragma unroll
    for (int t = 0; t < 4; ++t) { O[t][0] = 0.f; O[t][1] = 0.f; O[t][2] = 0.f; O[t][3] = 0.f; }
#pragma unroll
    for (int r = 0; r < 4; ++r) lacc[r] = 0.f;

    const int sr = tid >> 2, sg = tid & 3;
    const ushort* kbase = &K[((size_t)bh * SS + sr) * DKV + sg * 16];
    const ushort* vbase = &Vt[((size_t)bh * DKV + sr) * SS + sg * 16];
    const unsigned int* pmr[4];
#pragma unroll
    for (int r = 0; r < 4; ++r)
        pmr[r] = pm + ((size_t)b * SS + q0 + wv * 16 + quad * 4 + r) * 64;

    for (int kt = 0; kt < 32; ++kt) {
        // mask words issued early (read-only; land during staging+barrier)
        uint2 mw[4];
#pragma unroll
        for (int r = 0; r < 4; ++r) mw[r] = *(const uint2*)(pmr[r] + 2 * kt);

        __syncthreads();   // prior tile's frag reads done before restaging
        *(uint4*)&Ks[sr][sg * 16]     = *(const uint4*)kbase;
        *(uint4*)&Ks[sr][sg * 16 + 8] = *(const uint4*)(kbase + 8);
        *(uint4*)&Vs[sr][sg * 16]     = *(const uint4*)vbase;
        *(uint4*)&Vs[sr][sg * 16 + 8] = *(const uint4*)(vbase + 8);
        kbase += 64 * DKV;
        vbase += 64;
        __syncthreads();

        f32x4 sc[4];
        __builtin_amdgcn_s_setprio(1);
#pragma unroll
        for (int t = 0; t < 4; ++t) {
            bf16x8 b0 = *(const bf16x8*)&Ks[t * 16 + L][quad * 8];
            bf16x8 b1 = *(const bf16x8*)&Ks[t * 16 + L][32 + quad * 8];
            f32x4 c; c[0] = 0.f; c[1] = 0.f; c[2] = 0.f; c[3] = 0.f;
            c = MFMA16(aq0, b0, c);
            c = MFMA16(aq1, b1, c);
            sc[t] = c;
        }
        __builtin_amdgcn_s_setprio(0);

#pragma unroll
        for (int r = 0; r < 4; ++r) {
            const unsigned mx = mw[r].x, my = mw[r].y;
#pragma unroll
            for (int t = 0; t < 4; ++t) {
                const float s = fminf(sc[t][r], 30.f);
                const float e = __expf(s);
                const unsigned wsel = (t & 2) ? my : mx;
                const float p = ((wsel >> ((t & 1) * 16 + L)) & 1u) ? e : 0.f;
                lacc[r] += p;
                Ps[wv * 16 + quad * 4 + r][t * 16 + L] = f2bf_t(p);
            }
        }

        bf16x8 ap0 = *(const bf16x8*)&Ps[wv * 16 + L][quad * 8];
        bf16x8 ap1 = *(const bf16x8*)&Ps[wv * 16 + L][32 + quad * 8];
        __builtin_amdgcn_s_setprio(1);
#pragma unroll
        for (int t = 0; t < 4; ++t) {
            bf16x8 v0 = *(const bf16x8*)&Vs[t * 16 + L][quad * 8];
            bf16x8 v1 = *(const bf16x8*)&Vs[t * 16 + L][32 + quad * 8];
            O[t] = MFMA16(ap0, v0, O[t]);
            O[t] = MFMA16(ap1, v1, O[t]);
        }
        __builtin_amdgcn_s_setprio(0);
    }

    float inv[4];
#pragma unroll
    for (int r = 0; r < 4; ++r) {
        float l = lacc[r];
#pragma unroll
        for (int off = 1; off < 16; off <<= 1) l += __shfl_xor(l, off, 64);
        inv[r] = 1.f / l;
    }
#pragma unroll
    for (int t = 0; t < 4; ++t)
#pragma unroll
        for (int r = 0; r < 4; ++r) {
            const int qg = q0 + wv * 16 + quad * 4 + r;
            Xo[((size_t)b * SS + qg) * DM + h * DKV + t * 16 + L] = f2bf(O[t][r] * inv[r]);
        }
}

// =====================================================================
// Output projection — exact round-3 body: X @ Wt2 + query -> fp32 OutF.
// =====================================================================
__global__ __launch_bounds__(256) void oproj_mfma(
    const ushort* __restrict__ Xin, const ushort* __restrict__ Wt,
    const void* __restrict__ Qres, float* __restrict__ OutF)
{
    __shared__ __align__(16) ushort Asf[2][4096];
    __shared__ __align__(16) ushort Bsf[2][4096];

    const int mq = sniff_local(Qres, 4096);

    const int tid = threadIdx.x;
    const int lane = tid & 63, wv = tid >> 6;
    const int quad = lane >> 4, L = lane & 15;
    const int bid = blockIdx.y * gridDim.x + blockIdx.x;
    const int swz = (bid & 7) * 64 + (bid >> 3);
    const int m0 = (swz >> 3) * 128, n0 = (swz & 7) * 128;
    const int wm = (wv >> 1) * 64, wn = (wv & 1) * 64;

    const int e0 = (wv * 2 + 0) * 512 + lane * 8;
    const int e1 = (wv * 2 + 1) * 512 + lane * 8;
    const ushort* gA0 = Xin + (size_t)(m0 + (e0 >> 5)) * DM + (e0 & 31);
    const ushort* gA1 = Xin + (size_t)(m0 + (e1 >> 5)) * DM + (e1 & 31);
    const ushort* gB0 = Wt  + (size_t)(n0 + (e0 >> 5)) * DM + (e0 & 31);
    const ushort* gB1 = Wt  + (size_t)(n0 + (e1 >> 5)) * DM + (e1 & 31);

    f32x4 acc[4][4];
#pragma unroll
    for (int i = 0; i < 4; ++i)
#pragma unroll
        for (int j = 0; j < 4; ++j) { acc[i][j][0] = 0.f; acc[i][j][1] = 0.f; acc[i][j][2] = 0.f; acc[i][j][3] = 0.f; }

    gl_lds16(gA0, &Asf[0][e0]);
    gl_lds16(gA1, &Asf[0][e1]);
    gl_lds16(gB0, &Bsf[0][e0]);
    gl_lds16(gB1, &Bsf[0][e1]);
    wait_vm0_barrier();

    int cur = 0;
    for (int kt = 0; kt < 31; ++kt) {
        const int kn = (kt + 1) * 32;
        gl_lds16(gA0 + kn, &Asf[cur ^ 1][e0]);
        gl_lds16(gA1 + kn, &Asf[cur ^ 1][e1]);
        gl_lds16(gB0 + kn, &Bsf[cur ^ 1][e0]);
        gl_lds16(gB1 + kn, &Bsf[cur ^ 1][e1]);

        bf16x8 af[4], bfr[4];
#pragma unroll
        for (int tm = 0; tm < 4; ++tm) af[tm] = *(const bf16x8*)&Asf[cur][(wm + tm * 16 + L) * 32 + quad * 8];
#pragma unroll
        for (int tn = 0; tn < 4; ++tn) bfr[tn] = *(const bf16x8*)&Bsf[cur][(wn + tn * 16 + L) * 32 + quad * 8];
#pragma unroll
        for (int tm = 0; tm < 4; ++tm)
#pragma unroll
            for (int tn = 0; tn < 4; ++tn)
                acc[tm][tn] = MFMA16(af[tm], bfr[tn], acc[tm][tn]);

        wait_vm0_barrier();
        cur ^= 1;
    }
    {
        bf16x8 af[4], bfr[4];
#pragma unroll
        for (int tm = 0; tm < 4; ++tm) af[tm] = *(const bf16x8*)&Asf[cur][(wm + tm * 16 + L) * 32 + quad * 8];
#pragma unroll
        for (int tn = 0; tn < 4; ++tn) bfr[tn] = *(const bf16x8*)&Bsf[cur][(wn + tn * 16 + L) * 32 + quad * 8];
#pragma unroll
        for (int tm = 0; tm < 4; ++tm)
#pragma unroll
            for (int tn = 0; tn < 4; ++tn)
                acc[tm][tn] = MFMA16(af[tm], bfr[tn], acc[tm][tn]);
    }

#pragma unroll
    for (int tm = 0; tm < 4; ++tm)
#pragma unroll
        for (int tn = 0; tn < 4; ++tn)
#pragma unroll
            for (int r = 0; r < 4; ++r) {
                const int mm = m0 + wm + tm * 16 + quad * 4 + r;
                const int n = n0 + wn + tn * 16 + L;
                const size_t idx = (size_t)mm * DM + n;
                OutF[idx] = acc[tm][tn][r] + loadS(Qres, mq, idx);
            }
}

// =====================================================================
// LayerNorm: reads OutF (fp32, ws), writes final d_out. 1 row per wave.
// =====================================================================
__global__ __launch_bounds__(256) void ln_k(
    const float* __restrict__ In, float* __restrict__ Out,
    const void* __restrict__ G, const void* __restrict__ Bt)
{
    const int mg = sniff_local(G, 1024);
    const int mb = sniff_local(Bt, 1024);

    const int tid = threadIdx.x, wv = tid >> 6, lane = tid & 63;
    const int row = blockIdx.x * 4 + wv;
    const size_t base = (size_t)row * DM + lane * 16;

    float v[16];
    float s = 0.f, q = 0.f;
#pragma unroll
    for (int j = 0; j < 16; j += 4) {
        float4 t = *(const float4*)&In[base + j];
        v[j] = t.x; v[j+1] = t.y; v[j+2] = t.z; v[j+3] = t.w;
        s += t.x + t.y + t.z + t.w;
        q += t.x*t.x + t.y*t.y + t.z*t.z + t.w*t.w;
    }
#pragma unroll
    for (int off = 1; off < 64; off <<= 1) {
        s += __shfl_xor(s, off, 64);
        q += __shfl_xor(q, off, 64);
    }
    const float mu = s * (1.f / 1024.f);
    const float var = q * (1.f / 1024.f) - mu * mu;
    const float inv = rsqrtf(var + LNEPS);

    float gj[16], bj[16];
#pragma unroll
    for (int j = 0; j < 16; j += 4) {
        load4m(G,  mg, (size_t)lane * 16 + j, gj + j);
        load4m(Bt, mb, (size_t)lane * 16 + j, bj + j);
    }
#pragma unroll
    for (int j = 0; j < 16; j += 4) {
        float4 o;
        o.x = (v[j]   - mu) * inv * gj[j]   + bj[j];
        o.y = (v[j+1] - mu) * inv * gj[j+1] + bj[j+1];
        o.z = (v[j+2] - mu) * inv * gj[j+2] + bj[j+2];
        o.w = (v[j+3] - mu) * inv * gj[j+3] + bj[j+3];
        *(float4*)&Out[base + j] = o;
    }
}

// =====================================================================
extern "C" void kernel_launch(void* const* d_in, const int* in_sizes, int n_in,
                              void* d_out, int out_size, void* d_ws, size_t ws_size,
                              hipStream_t stream)
{
    const void* query = d_in[0];
    const void* key_i = d_in[1];
    const void* value = d_in[2];
    const int*  mask  = (const int*)d_in[3];
    const void* w_qs  = d_in[4];
    const void* w_ks  = d_in[5];
    const void* w_vs  = d_in[6];
    const void* w_out = d_in[7];
    const void* ln_g  = d_in[8];
    const void* ln_b  = d_in[9];
    float* out = (float*)d_out;

    // ws (64MB): [pad 256B][Qw 16][Kw 16][Vw 16][Xw 16]
    //   Xw hosts Abv during prep/projqv, then Abk, then attn's X output.
    //   OutF (32MB fp32) = Qw+Kw region, live only post-attn.
    // d_out (32MB, final write in ln_k):
    //   pmask@0 (2), Wtq@2, Wtk@4, Wtv@6, Wt2@8 (2 each), Abq@10..26.
    const size_t PE = (size_t)BB * HH * SS * DKV;  // 8,388,608
    ushort* Qw = (ushort*)((char*)d_ws + 256);
    ushort* Kw = Qw + PE;
    ushort* Vw = Kw + PE;   // transposed layout [bh][d][s]
    ushort* Xw = Vw + PE;
    float*  OutF = (float*)Qw;
    unsigned int* pmask = (unsigned int*)d_out;
    ushort* Wtq = (ushort*)((char*)d_out + (2 << 20));
    ushort* Wtk = (ushort*)((char*)d_out + (4 << 20));
    ushort* Wtv = (ushort*)((char*)d_out + (6 << 20));
    ushort* Wt2 = (ushort*)((char*)d_out + (8 << 20));
    ushort* Abq = (ushort*)((char*)d_out + (10 << 20));
    ushort* Abv = Xw;
    ushort* Abk = Xw;   // reused after projqv consumes Abv

    prep<<<7168, 256, 0, stream>>>(mask, pmask, w_qs, w_ks, w_vs, w_out,
                                   Wtq, Wtk, Wtv, Wt2, query, value, Abq, Abv);

    ProjArgs pqv;
    pqv.A[0] = Abq; pqv.Wt[0] = Wtq; pqv.Out[0] = Qw; pqv.vmode[0] = 0; pqv.scale[0] = 0.125f;
    pqv.A[1] = Abv; pqv.Wt[1] = Wtv; pqv.Out[1] = Vw; pqv.vmode[1] = 1; pqv.scale[1] = 1.0f;
    proj_mfma<<<dim3(8, 64, 2), 256, 0, stream>>>(pqv);

    aconv_k<<<2048, 256, 0, stream>>>(key_i, Abk);

    ProjArgs pk;
    pk.A[0] = Abk; pk.Wt[0] = Wtk; pk.Out[0] = Kw; pk.vmode[0] = 0; pk.scale[0] = 1.0f;
    pk.A[1] = Abk; pk.Wt[1] = Wtk; pk.Out[1] = Kw; pk.vmode[1] = 0; pk.scale[1] = 1.0f;
    proj_mfma<<<dim3(8, 64, 1), 256, 0, stream>>>(pk);

    attn_mfma<<<dim3(32, 64), 256, 0, stream>>>(Qw, Kw, Vw, pmask, Xw);

    oproj_mfma<<<dim3(8, 64), 256, 0, stream>>>(Xw, Wt2, query, OutF);

    ln_k<<<2048, 256, 0, stream>>>(OutF, out, ln_g, ln_b);
}

// Round 11
// 532.148 us; speedup vs baseline: 1.3002x; 1.0188x over previous
//
#include <hip/hip_runtime.h>

#define BB   4
#define SS   2048
#define HH   16
#define DM   1024
#define DKV  64
#define LNEPS 1e-6f

#define MD_BF16 0
#define MD_F32  1
#define MD_F16  2

typedef __attribute__((ext_vector_type(8))) short bf16x8;
typedef __attribute__((ext_vector_type(4))) float f32x4;
#define MFMA16(a,b,c) __builtin_amdgcn_mfma_f32_16x16x32_bf16(a,b,c,0,0,0)

// async global->LDS DMA, 16B per lane (dest = wave-uniform base + lane*16)
__device__ __forceinline__ void gl_lds16(const ushort* g, ushort* l) {
    __builtin_amdgcn_global_load_lds(
        (const __attribute__((address_space(1))) void*)g,
        (__attribute__((address_space(3))) void*)l, 16, 0, 0);
}
__device__ __forceinline__ void wait_vm0_barrier() {
    asm volatile("s_waitcnt vmcnt(0)" ::: "memory");
    __builtin_amdgcn_s_barrier();
}

// ---------- dtype helpers ----------
__device__ __forceinline__ float2 unpack2(unsigned int u) {
    union { unsigned int i; float f; } a, b;
    a.i = u << 16;
    b.i = u & 0xffff0000u;
    return make_float2(a.f, b.f);
}
__device__ __forceinline__ unsigned short f2bf(float f) {   // RNE
    union { float f; unsigned int i; } c; c.f = f;
    unsigned int u = c.i;
    unsigned int r = u + 0x7fffu + ((u >> 16) & 1u);
    return (unsigned short)(r >> 16);
}
__device__ __forceinline__ unsigned short f2bf_t(float f) { // truncate
    union { float f; unsigned int i; } c; c.f = f;
    return (unsigned short)(c.i >> 16);
}
__device__ __forceinline__ float h2f(unsigned int bits16) {
    unsigned short s = (unsigned short)bits16;
    _Float16 x;
    __builtin_memcpy(&x, &s, 2);
    return (float)x;
}
__device__ __forceinline__ void load4m(const void* p, int mode, size_t e0, float* o) {
    if (mode == MD_F32) {
        float4 v = *(const float4*)((const float*)p + e0);
        o[0] = v.x; o[1] = v.y; o[2] = v.z; o[3] = v.w;
    } else {
        uint2 u = *(const uint2*)((const ushort*)p + e0);
        if (mode == MD_BF16) {
            float2 a = unpack2(u.x), b = unpack2(u.y);
            o[0] = a.x; o[1] = a.y; o[2] = b.x; o[3] = b.y;
        } else {
            o[0] = h2f(u.x & 0xFFFFu); o[1] = h2f(u.x >> 16);
            o[2] = h2f(u.y & 0xFFFFu); o[3] = h2f(u.y >> 16);
        }
    }
}
__device__ __forceinline__ float loadS(const void* p, int mode, size_t i) {
    if (mode == MD_F32) return ((const float*)p)[i];
    unsigned short u = ((const ushort*)p)[i];
    if (mode == MD_BF16) { union { unsigned i; float f; } c; c.i = (unsigned)u << 16; return c.f; }
    return h2f(u);
}

// raw 16-elem load + convert (same rounding chain as all prior rounds)
__device__ __forceinline__ void loadAraw(const void* p, int m, size_t e, uint4* r) {
    if (m == MD_F32) {
        const float* f = (const float*)p + e;
        r[0] = *(const uint4*)(f);
        r[1] = *(const uint4*)(f + 4);
        r[2] = *(const uint4*)(f + 8);
        r[3] = *(const uint4*)(f + 12);
    } else {
        const ushort* s = (const ushort*)p + e;
        r[0] = *(const uint4*)s;
        r[1] = *(const uint4*)(s + 8);
    }
}
__device__ __forceinline__ void cvtA16(const uint4* r, int m, uint4* o2) {
    union { ushort u[16]; uint4 v[2]; } o;
    if (m == MD_F32) {
        const float* f = (const float*)r;
#pragma unroll
        for (int j = 0; j < 16; ++j) o.u[j] = f2bf(f[j]);
    } else if (m == MD_BF16) {
        o.v[0] = r[0]; o.v[1] = r[1];
    } else {
        const ushort* s = (const ushort*)r;
#pragma unroll
        for (int j = 0; j < 16; ++j) o.u[j] = f2bf(h2f(s[j]));
    }
    o2[0] = o.v[0]; o2[1] = o.v[1];
}

// per-block dtype sniff (same function of same bytes everywhere)
__device__ __forceinline__ int sniff_local(const void* p_, int nhalf) {
    __shared__ int cE, cO;
    const ushort* p = (const ushort*)p_;
    if (threadIdx.x == 0) { cE = 0; cO = 0; }
    __syncthreads();
    int e = 0, o = 0;
    for (int i = threadIdx.x; i < nhalf; i += 256) {
        unsigned ex = (p[i] >> 7) & 0xFFu;
        int hit = (ex < 100u || ex == 0xFFu) ? 1 : 0;
        if (i & 1) o += hit; else e += hit;
    }
    atomicAdd(&cE, e);
    atomicAdd(&cO, o);
    __syncthreads();
    const int total = cE + cO;
    return (total < 48) ? MD_BF16 : ((cO * 4 < cE) ? MD_F32 : MD_F16);
}

// ---------- shared bodies ----------
__device__ __forceinline__ void wtrans_body(
    const void* __restrict__ W, ushort* __restrict__ Wt, int m, int sub)
{
    __shared__ ushort T[64][68];
    const int tid = threadIdx.x;
    const int n0 = (sub & 15) * 64, k0 = (sub >> 4) * 64;

    const int r = tid >> 2, c = (tid & 3) * 16;
    float t[4];
#pragma unroll
    for (int j = 0; j < 4; ++j) {
        load4m(W, m, (size_t)(k0 + r) * DM + n0 + c + 4 * j, t);
#pragma unroll
        for (int i = 0; i < 4; ++i) T[r][c + 4 * j + i] = f2bf(t[i]);
    }
    __syncthreads();

    const int rn = tid >> 2, ck = (tid & 3) * 16;
    union { ushort u[8]; uint4 v; } p0, p1;
#pragma unroll
    for (int j = 0; j < 8; ++j) { p0.u[j] = T[ck + j][rn]; p1.u[j] = T[ck + 8 + j][rn]; }
    ushort* op = &Wt[(size_t)(n0 + rn) * DM + k0 + ck];
    *(uint4*)op = p0.v;
    *(uint4*)(op + 8) = p1.v;
}

__device__ __forceinline__ void aconv_body(
    const void* __restrict__ A, ushort* __restrict__ Ab, int bidl)
{
    const int m = sniff_local(A, 4096);
    const size_t e0 = ((size_t)bidl * 256 + threadIdx.x) * 16;
    uint4 r[4], o[2];
    loadAraw(A, m, e0, r);
    cvtA16(r, m, o);
    *(uint4*)&Ab[e0]     = o[0];
    *(uint4*)&Ab[e0 + 8] = o[1];
}

// =====================================================================
// prep (one launch, 7168 blocks):
//   [0,2048)    mask bit-pack -> pm (2MB)
//   [2048,3072) 4x weight transpose (w_qs,w_ks,w_vs,w_out -> Wt*)
//   [3072,5120) aconv(query) -> Abq
//   [5120,7168) aconv(value) -> Abv
// =====================================================================
__global__ __launch_bounds__(256) void prep(
    const int* __restrict__ mask, unsigned int* __restrict__ pm,
    const void* __restrict__ w_qs, const void* __restrict__ w_ks,
    const void* __restrict__ w_vs, const void* __restrict__ w_out,
    ushort* __restrict__ Wtq, ushort* __restrict__ Wtk,
    ushort* __restrict__ Wtv, ushort* __restrict__ Wt2,
    const void* __restrict__ query, const void* __restrict__ value,
    ushort* __restrict__ Abq, ushort* __restrict__ Abv)
{
    const int bid = blockIdx.x;
    if (bid < 2048) {
        const int w = bid * 256 + threadIdx.x;
        const int* p = mask + (size_t)w * 32;
        unsigned int bits = 0u;
#pragma unroll
        for (int j = 0; j < 8; ++j) {
            int4 v = *(const int4*)(p + j * 4);
            bits |= (v.x ? 1u : 0u) << (4 * j);
            bits |= (v.y ? 1u : 0u) << (4 * j + 1);
            bits |= (v.z ? 1u : 0u) << (4 * j + 2);
            bits |= (v.w ? 1u : 0u) << (4 * j + 3);
        }
        pm[w] = bits;
    } else if (bid < 3072) {
        const int b2 = bid - 2048;
        const int g = b2 >> 8, sub = b2 & 255;
        const void* W = (g == 0) ? w_qs : (g == 1) ? w_ks : (g == 2) ? w_vs : w_out;
        ushort* Wt = (g == 0) ? Wtq : (g == 1) ? Wtk : (g == 2) ? Wtv : Wt2;
        wtrans_body(W, Wt, sniff_local(W, 4096), sub);
    } else if (bid < 5120) {
        aconv_body(query, Abq, bid - 3072);
    } else {
        aconv_body(value, Abv, bid - 5120);
    }
}

// standalone aconv for key (runs after projqv frees the Abv/Xw region)
__global__ __launch_bounds__(256) void aconv_k(
    const void* __restrict__ A, ushort* __restrict__ Ab)
{
    aconv_body(A, Ab, blockIdx.x);
}

// =====================================================================
// MFMA projection GEMM — round-3 proven body (BK=32, dbuf
// global_load_lds, XCD-chunked swizzle), z-dispatch over 2 GEMMs.
// vmode==1 (V): epilogue transposes through LDS (overlaid on the dead
// staging buffers) so global stores are 16B-contiguous instead of the
// old 2B/4KB-stride scatter.  LDS buffers addressed via computed
// offsets (no LDS-pointer array — hipcc rejects that initializer).
// =====================================================================
struct ProjArgs {
    const ushort* A[2]; const ushort* Wt[2]; ushort* Out[2];
    int vmode[2]; float scale[2];
};

#define ASF(BUF) (SMEM + (BUF) * 4096)
#define BSF(BUF) (SMEM + 8192 + (BUF) * 4096)

__global__ __launch_bounds__(256) void proj_mfma(ProjArgs pa)
{
    // overlay: staging A @ [0,8192), B @ [8192,16384);
    // V-epilogue transpose T[128][136] reuses the whole region (17408 ush).
    __shared__ __align__(16) ushort SMEM[17408];

    const int z = blockIdx.z;
    const ushort* A  = pa.A[z];
    const ushort* Wt = pa.Wt[z];
    ushort* Out = pa.Out[z];
    const int vmode = pa.vmode[z];
    const float scale = pa.scale[z];

    const int tid = threadIdx.x;
    const int lane = tid & 63, wv = tid >> 6;
    const int quad = lane >> 4, L = lane & 15;
    const int bid = blockIdx.y * gridDim.x + blockIdx.x;   // 512 per z
    const int swz = (bid & 7) * 64 + (bid >> 3);           // XCD-chunked
    const int m0 = (swz >> 3) * 128, n0 = (swz & 7) * 128;
    const int wm = (wv >> 1) * 64, wn = (wv & 1) * 64;

    const int e0 = (wv * 2 + 0) * 512 + lane * 8;
    const int e1 = (wv * 2 + 1) * 512 + lane * 8;
    const ushort* gA0 = A  + (size_t)(m0 + (e0 >> 5)) * DM + (e0 & 31);
    const ushort* gA1 = A  + (size_t)(m0 + (e1 >> 5)) * DM + (e1 & 31);
    const ushort* gB0 = Wt + (size_t)(n0 + (e0 >> 5)) * DM + (e0 & 31);
    const ushort* gB1 = Wt + (size_t)(n0 + (e1 >> 5)) * DM + (e1 & 31);

    f32x4 acc[4][4];
#pragma unroll
    for (int i = 0; i < 4; ++i)
#pragma unroll
        for (int j = 0; j < 4; ++j) { acc[i][j][0] = 0.f; acc[i][j][1] = 0.f; acc[i][j][2] = 0.f; acc[i][j][3] = 0.f; }

    gl_lds16(gA0, ASF(0) + e0);
    gl_lds16(gA1, ASF(0) + e1);
    gl_lds16(gB0, BSF(0) + e0);
    gl_lds16(gB1, BSF(0) + e1);
    wait_vm0_barrier();

    int cur = 0;
    for (int kt = 0; kt < 31; ++kt) {
        const int kn = (kt + 1) * 32;
        gl_lds16(gA0 + kn, ASF(cur ^ 1) + e0);
        gl_lds16(gA1 + kn, ASF(cur ^ 1) + e1);
        gl_lds16(gB0 + kn, BSF(cur ^ 1) + e0);
        gl_lds16(gB1 + kn, BSF(cur ^ 1) + e1);

        bf16x8 af[4], bfr[4];
#pragma unroll
        for (int tm = 0; tm < 4; ++tm) af[tm] = *(const bf16x8*)(ASF(cur) + (wm + tm * 16 + L) * 32 + quad * 8);
#pragma unroll
        for (int tn = 0; tn < 4; ++tn) bfr[tn] = *(const bf16x8*)(BSF(cur) + (wn + tn * 16 + L) * 32 + quad * 8);
#pragma unroll
        for (int tm = 0; tm < 4; ++tm)
#pragma unroll
            for (int tn = 0; tn < 4; ++tn)
                acc[tm][tn] = MFMA16(af[tm], bfr[tn], acc[tm][tn]);

        wait_vm0_barrier();
        cur ^= 1;
    }
    {
        bf16x8 af[4], bfr[4];
#pragma unroll
        for (int tm = 0; tm < 4; ++tm) af[tm] = *(const bf16x8*)(ASF(cur) + (wm + tm * 16 + L) * 32 + quad * 8);
#pragma unroll
        for (int tn = 0; tn < 4; ++tn) bfr[tn] = *(const bf16x8*)(BSF(cur) + (wn + tn * 16 + L) * 32 + quad * 8);
#pragma unroll
        for (int tm = 0; tm < 4; ++tm)
#pragma unroll
            for (int tn = 0; tn < 4; ++tn)
                acc[tm][tn] = MFMA16(af[tm], bfr[tn], acc[tm][tn]);
    }

    if (!vmode) {
        // direct stores: consecutive L -> consecutive d (coalesced 32B runs)
#pragma unroll
        for (int tm = 0; tm < 4; ++tm)
#pragma unroll
            for (int tn = 0; tn < 4; ++tn)
#pragma unroll
                for (int r = 0; r < 4; ++r) {
                    const int mm = m0 + wm + tm * 16 + quad * 4 + r;
                    const int n = n0 + wn + tn * 16 + L;
                    const int b = mm >> 11, s = mm & 2047;
                    const int h = n >> 6, d = n & 63;
                    Out[((size_t)(b * HH + h) * SS + s) * DKV + d] =
                        f2bf(acc[tm][tn][r] * scale);
                }
    } else {
        // V: transpose through LDS, then 16B-contiguous stores
        __syncthreads();   // all waves done reading staging LDS
        ushort (*T)[136] = (ushort (*)[136])SMEM;
#pragma unroll
        for (int tm = 0; tm < 4; ++tm)
#pragma unroll
            for (int tn = 0; tn < 4; ++tn)
#pragma unroll
                for (int r = 0; r < 4; ++r)
                    T[wn + tn * 16 + L][wm + tm * 16 + quad * 4 + r] =
                        f2bf(acc[tm][tn][r] * scale);
        __syncthreads();

        const int row = tid >> 1, half = tid & 1;   // row = local n (d)
        const int ng = n0 + row;
        const int h = ng >> 6, d = ng & 63;
        const int b = m0 >> 11, s0v = m0 & 2047;
        ushort* dst = Out + ((size_t)(b * HH + h) * DKV + d) * SS + s0v + half * 64;
        const ushort* srcT = &T[row][half * 64];
#pragma unroll
        for (int j = 0; j < 8; ++j)
            *(uint4*)(dst + j * 8) = *(const uint4*)(srcT + j * 8);
    }
}

// =====================================================================
// MFMA flash attention — round-3/9 proven body (158.9us) with one
// addition: Ps XOR-swizzle.  Writer stores col^(quad<<3) (writer's
// (row>>2)&3 == quad); reader's 8-aligned block moves to
// (quad*8)^(((L>>2)&3)<<3) — bijective per row, contiguity and 16B
// alignment preserved.  Kills the 4-way conflict on the 16 scalar
// P-stores per thread per tile (the 1.887e7 counter).
// =====================================================================
__global__ __launch_bounds__(256) void attn_mfma(
    const ushort* __restrict__ Q, const ushort* __restrict__ K,
    const ushort* __restrict__ Vt, const unsigned int* __restrict__ pm,
    ushort* __restrict__ Xo)
{
    __shared__ __align__(16) ushort Ks[64][72];
    __shared__ __align__(16) ushort Vs[64][72];
    __shared__ __align__(16) ushort Ps[64][72];

    const int tid = threadIdx.x;
    const int lane = tid & 63, wv = tid >> 6;
    const int quad = lane >> 4, L = lane & 15;
    const int bid = blockIdx.y * gridDim.x + blockIdx.x;
    const int swz = (bid & 7) * 256 + (bid >> 3);
    const int bh = swz >> 5, b = bh >> 4, h = bh & 15;
    const int q0 = (swz & 31) * 64;

    const ushort* qp = &Q[((size_t)bh * SS + q0 + wv * 16 + L) * DKV + quad * 8];
    const bf16x8 aq0 = *(const bf16x8*)qp;
    const bf16x8 aq1 = *(const bf16x8*)(qp + 32);

    f32x4 O[4];
    float lacc[4];
#pragma unroll
    for (int t = 0; t < 4; ++t) { O[t][0] = 0.f; O[t][1] = 0.f; O[t][2] = 0.f; O[t][3] = 0.f; }
#pragma unroll
    for (int r = 0; r < 4; ++r) lacc[r] = 0.f;

    const int sr = tid >> 2, sg = tid & 3;
    const ushort* kbase = &K[((size_t)bh * SS + sr) * DKV + sg * 16];
    const ushort* vbase = &Vt[((size_t)bh * DKV + sr) * SS + sg * 16];
    const unsigned int* pmr[4];
#pragma unroll
    for (int r = 0; r < 4; ++r)
        pmr[r] = pm + ((size_t)b * SS + q0 + wv * 16 + quad * 4 + r) * 64;

    const int wsw = quad << 3;                 // writer swizzle (row's (row>>2)&3 == quad)
    const int fr  = ((L >> 2) & 3) << 3;       // reader swizzle for row wv*16+L

    for (int kt = 0; kt < 32; ++kt) {
        // mask words issued early (read-only; land during staging+barrier)
        uint2 mw[4];
#pragma unroll
        for (int r = 0; r < 4; ++r) mw[r] = *(const uint2*)(pmr[r] + 2 * kt);

        __syncthreads();   // prior tile's frag reads done before restaging
        *(uint4*)&Ks[sr][sg * 16]     = *(const uint4*)kbase;
        *(uint4*)&Ks[sr][sg * 16 + 8] = *(const uint4*)(kbase + 8);
        *(uint4*)&Vs[sr][sg * 16]     = *(const uint4*)vbase;
        *(uint4*)&Vs[sr][sg * 16 + 8] = *(const uint4*)(vbase + 8);
        kbase += 64 * DKV;
        vbase += 64;
        __syncthreads();

        f32x4 sc[4];
        __builtin_amdgcn_s_setprio(1);
#pragma unroll
        for (int t = 0; t < 4; ++t) {
            bf16x8 b0 = *(const bf16x8*)&Ks[t * 16 + L][quad * 8];
            bf16x8 b1 = *(const bf16x8*)&Ks[t * 16 + L][32 + quad * 8];
            f32x4 c; c[0] = 0.f; c[1] = 0.f; c[2] = 0.f; c[3] = 0.f;
            c = MFMA16(aq0, b0, c);
            c = MFMA16(aq1, b1, c);
            sc[t] = c;
        }
        __builtin_amdgcn_s_setprio(0);

#pragma unroll
        for (int r = 0; r < 4; ++r) {
            const unsigned mx = mw[r].x, my = mw[r].y;
#pragma unroll
            for (int t = 0; t < 4; ++t) {
                const float s = fminf(sc[t][r], 30.f);
                const float e = __expf(s);
                const unsigned wsel = (t & 2) ? my : mx;
                const float p = ((wsel >> ((t & 1) * 16 + L)) & 1u) ? e : 0.f;
                lacc[r] += p;
                Ps[wv * 16 + quad * 4 + r][(t * 16 + L) ^ wsw] = f2bf_t(p);
            }
        }

        bf16x8 ap0 = *(const bf16x8*)&Ps[wv * 16 + L][(quad * 8) ^ fr];
        bf16x8 ap1 = *(const bf16x8*)&Ps[wv * 16 + L][32 + ((quad * 8) ^ fr)];
        __builtin_amdgcn_s_setprio(1);
#pragma unroll
        for (int t = 0; t < 4; ++t) {
            bf16x8 v0 = *(const bf16x8*)&Vs[t * 16 + L][quad * 8];
            bf16x8 v1 = *(const bf16x8*)&Vs[t * 16 + L][32 + quad * 8];
            O[t] = MFMA16(ap0, v0, O[t]);
            O[t] = MFMA16(ap1, v1, O[t]);
        }
        __builtin_amdgcn_s_setprio(0);
    }

    float inv[4];
#pragma unroll
    for (int r = 0; r < 4; ++r) {
        float l = lacc[r];
#pragma unroll
        for (int off = 1; off < 16; off <<= 1) l += __shfl_xor(l, off, 64);
        inv[r] = 1.f / l;
    }
#pragma unroll
    for (int t = 0; t < 4; ++t)
#pragma unroll
        for (int r = 0; r < 4; ++r) {
            const int qg = q0 + wv * 16 + quad * 4 + r;
            Xo[((size_t)b * SS + qg) * DM + h * DKV + t * 16 + L] = f2bf(O[t][r] * inv[r]);
        }
}

// =====================================================================
// Output projection — exact round-3 body: X @ Wt2 + query -> fp32 OutF.
// =====================================================================
__global__ __launch_bounds__(256) void oproj_mfma(
    const ushort* __restrict__ Xin, const ushort* __restrict__ Wt,
    const void* __restrict__ Qres, float* __restrict__ OutF)
{
    __shared__ __align__(16) ushort Asf[2][4096];
    __shared__ __align__(16) ushort Bsf[2][4096];

    const int mq = sniff_local(Qres, 4096);

    const int tid = threadIdx.x;
    const int lane = tid & 63, wv = tid >> 6;
    const int quad = lane >> 4, L = lane & 15;
    const int bid = blockIdx.y * gridDim.x + blockIdx.x;
    const int swz = (bid & 7) * 64 + (bid >> 3);
    const int m0 = (swz >> 3) * 128, n0 = (swz & 7) * 128;
    const int wm = (wv >> 1) * 64, wn = (wv & 1) * 64;

    const int e0 = (wv * 2 + 0) * 512 + lane * 8;
    const int e1 = (wv * 2 + 1) * 512 + lane * 8;
    const ushort* gA0 = Xin + (size_t)(m0 + (e0 >> 5)) * DM + (e0 & 31);
    const ushort* gA1 = Xin + (size_t)(m0 + (e1 >> 5)) * DM + (e1 & 31);
    const ushort* gB0 = Wt  + (size_t)(n0 + (e0 >> 5)) * DM + (e0 & 31);
    const ushort* gB1 = Wt  + (size_t)(n0 + (e1 >> 5)) * DM + (e1 & 31);

    f32x4 acc[4][4];
#pragma unroll
    for (int i = 0; i < 4; ++i)
#pragma unroll
        for (int j = 0; j < 4; ++j) { acc[i][j][0] = 0.f; acc[i][j][1] = 0.f; acc[i][j][2] = 0.f; acc[i][j][3] = 0.f; }

    gl_lds16(gA0, &Asf[0][e0]);
    gl_lds16(gA1, &Asf[0][e1]);
    gl_lds16(gB0, &Bsf[0][e0]);
    gl_lds16(gB1, &Bsf[0][e1]);
    wait_vm0_barrier();

    int cur = 0;
    for (int kt = 0; kt < 31; ++kt) {
        const int kn = (kt + 1) * 32;
        gl_lds16(gA0 + kn, &Asf[cur ^ 1][e0]);
        gl_lds16(gA1 + kn, &Asf[cur ^ 1][e1]);
        gl_lds16(gB0 + kn, &Bsf[cur ^ 1][e0]);
        gl_lds16(gB1 + kn, &Bsf[cur ^ 1][e1]);

        bf16x8 af[4], bfr[4];
#pragma unroll
        for (int tm = 0; tm < 4; ++tm) af[tm] = *(const bf16x8*)&Asf[cur][(wm + tm * 16 + L) * 32 + quad * 8];
#pragma unroll
        for (int tn = 0; tn < 4; ++tn) bfr[tn] = *(const bf16x8*)&Bsf[cur][(wn + tn * 16 + L) * 32 + quad * 8];
#pragma unroll
        for (int tm = 0; tm < 4; ++tm)
#pragma unroll
            for (int tn = 0; tn < 4; ++tn)
                acc[tm][tn] = MFMA16(af[tm], bfr[tn], acc[tm][tn]);

        wait_vm0_barrier();
        cur ^= 1;
    }
    {
        bf16x8 af[4], bfr[4];
#pragma unroll
        for (int tm = 0; tm < 4; ++tm) af[tm] = *(const bf16x8*)&Asf[cur][(wm + tm * 16 + L) * 32 + quad * 8];
#pragma unroll
        for (int tn = 0; tn < 4; ++tn) bfr[tn] = *(const bf16x8*)&Bsf[cur][(wn + tn * 16 + L) * 32 + quad * 8];
#pragma unroll
        for (int tm = 0; tm < 4; ++tm)
#pragma unroll
            for (int tn = 0; tn < 4; ++tn)
                acc[tm][tn] = MFMA16(af[tm], bfr[tn], acc[tm][tn]);
    }

#pragma unroll
    for (int tm = 0; tm < 4; ++tm)
#pragma unroll
        for (int tn = 0; tn < 4; ++tn)
#pragma unroll
            for (int r = 0; r < 4; ++r) {
                const int mm = m0 + wm + tm * 16 + quad * 4 + r;
                const int n = n0 + wn + tn * 16 + L;
                const size_t idx = (size_t)mm * DM + n;
                OutF[idx] = acc[tm][tn][r] + loadS(Qres, mq, idx);
            }
}

// =====================================================================
// LayerNorm: reads OutF (fp32, ws), writes final d_out. 1 row per wave.
// =====================================================================
__global__ __launch_bounds__(256) void ln_k(
    const float* __restrict__ In, float* __restrict__ Out,
    const void* __restrict__ G, const void* __restrict__ Bt)
{
    const int mg = sniff_local(G, 1024);
    const int mb = sniff_local(Bt, 1024);

    const int tid = threadIdx.x, wv = tid >> 6, lane = tid & 63;
    const int row = blockIdx.x * 4 + wv;
    const size_t base = (size_t)row * DM + lane * 16;

    float v[16];
    float s = 0.f, q = 0.f;
#pragma unroll
    for (int j = 0; j < 16; j += 4) {
        float4 t = *(const float4*)&In[base + j];
        v[j] = t.x; v[j+1] = t.y; v[j+2] = t.z; v[j+3] = t.w;
        s += t.x + t.y + t.z + t.w;
        q += t.x*t.x + t.y*t.y + t.z*t.z + t.w*t.w;
    }
#pragma unroll
    for (int off = 1; off < 64; off <<= 1) {
        s += __shfl_xor(s, off, 64);
        q += __shfl_xor(q, off, 64);
    }
    const float mu = s * (1.f / 1024.f);
    const float var = q * (1.f / 1024.f) - mu * mu;
    const float inv = rsqrtf(var + LNEPS);

    float gj[16], bj[16];
#pragma unroll
    for (int j = 0; j < 16; j += 4) {
        load4m(G,  mg, (size_t)lane * 16 + j, gj + j);
        load4m(Bt, mb, (size_t)lane * 16 + j, bj + j);
    }
#pragma unroll
    for (int j = 0; j < 16; j += 4) {
        float4 o;
        o.x = (v[j]   - mu) * inv * gj[j]   + bj[j];
        o.y = (v[j+1] - mu) * inv * gj[j+1] + bj[j+1];
        o.z = (v[j+2] - mu) * inv * gj[j+2] + bj[j+2];
        o.w = (v[j+3] - mu) * inv * gj[j+3] + bj[j+3];
        *(float4*)&Out[base + j] = o;
    }
}

// =====================================================================
extern "C" void kernel_launch(void* const* d_in, const int* in_sizes, int n_in,
                              void* d_out, int out_size, void* d_ws, size_t ws_size,
                              hipStream_t stream)
{
    const void* query = d_in[0];
    const void* key_i = d_in[1];
    const void* value = d_in[2];
    const int*  mask  = (const int*)d_in[3];
    const void* w_qs  = d_in[4];
    const void* w_ks  = d_in[5];
    const void* w_vs  = d_in[6];
    const void* w_out = d_in[7];
    const void* ln_g  = d_in[8];
    const void* ln_b  = d_in[9];
    float* out = (float*)d_out;

    // ws (64MB): [pad 256B][Qw 16][Kw 16][Vw 16][Xw 16]
    //   Xw hosts Abv during prep/projqv, then Abk, then attn's X output.
    //   OutF (32MB fp32) = Qw+Kw region, live only post-attn.
    // d_out (32MB, final write in ln_k):
    //   pmask@0 (2), Wtq@2, Wtk@4, Wtv@6, Wt2@8 (2 each), Abq@10..26.
    const size_t PE = (size_t)BB * HH * SS * DKV;  // 8,388,608
    ushort* Qw = (ushort*)((char*)d_ws + 256);
    ushort* Kw = Qw + PE;
    ushort* Vw = Kw + PE;   // transposed layout [bh][d][s]
    ushort* Xw = Vw + PE;
    float*  OutF = (float*)Qw;
    unsigned int* pmask = (unsigned int*)d_out;
    ushort* Wtq = (ushort*)((char*)d_out + (2 << 20));
    ushort* Wtk = (ushort*)((char*)d_out + (4 << 20));
    ushort* Wtv = (ushort*)((char*)d_out + (6 << 20));
    ushort* Wt2 = (ushort*)((char*)d_out + (8 << 20));
    ushort* Abq = (ushort*)((char*)d_out + (10 << 20));
    ushort* Abv = Xw;
    ushort* Abk = Xw;   // reused after projqv consumes Abv

    prep<<<7168, 256, 0, stream>>>(mask, pmask, w_qs, w_ks, w_vs, w_out,
                                   Wtq, Wtk, Wtv, Wt2, query, value, Abq, Abv);

    ProjArgs pqv;
    pqv.A[0] = Abq; pqv.Wt[0] = Wtq; pqv.Out[0] = Qw; pqv.vmode[0] = 0; pqv.scale[0] = 0.125f;
    pqv.A[1] = Abv; pqv.Wt[1] = Wtv; pqv.Out[1] = Vw; pqv.vmode[1] = 1; pqv.scale[1] = 1.0f;
    proj_mfma<<<dim3(8, 64, 2), 256, 0, stream>>>(pqv);

    aconv_k<<<2048, 256, 0, stream>>>(key_i, Abk);

    ProjArgs pk;
    pk.A[0] = Abk; pk.Wt[0] = Wtk; pk.Out[0] = Kw; pk.vmode[0] = 0; pk.scale[0] = 1.0f;
    pk.A[1] = Abk; pk.Wt[1] = Wtk; pk.Out[1] = Kw; pk.vmode[1] = 0; pk.scale[1] = 1.0f;
    proj_mfma<<<dim3(8, 64, 1), 256, 0, stream>>>(pk);

    attn_mfma<<<dim3(32, 64), 256, 0, stream>>>(Qw, Kw, Vw, pmask, Xw);

    oproj_mfma<<<dim3(8, 64), 256, 0, stream>>>(Xw, Wt2, query, OutF);

    ln_k<<<2048, 256, 0, stream>>>(OutF, out, ln_g, ln_b);
}